// Round 6
// baseline (650.854 us; speedup 1.0000x reference)
//
#include <hip/hip_runtime.h>
#include <math.h>

// ---------------------------------------------------------------------------
// GAT 2-layer + mean-pool + classifier, fp32 end-to-end.
//  - CSR(dst) built on-device (atomic-free scatter via rank array)
//  - softmax denominators factor out; no segment-max (logits O(1), fp32 safe)
//  - a_src EMBEDDED in each H row (row stride RS = CH + HEADS + pad) so the
//    aggregation's weight input rides the same gather stream as the row
//  - self loops analytic; dst-centric aggregation; no fp atomics
//  - agg loop structure frozen at the measured ~3.9 TB/s replicated-gather
//    wall (FETCH at the 8-XCD replication floor) — do not re-tune
// ---------------------------------------------------------------------------

// ---------------- CSR build ----------------

// histogram + per-edge rank (old count value) in one pass
__global__ void k_hist(const int* __restrict__ dst, int* __restrict__ counts,
                       int* __restrict__ rank, int e){
  int i = blockIdx.x * 256 + threadIdx.x;
  if (i < e) rank[i] = atomicAdd(&counts[dst[i]], 1);
}

__global__ __launch_bounds__(1024) void k_scan1(const int* __restrict__ counts,
                                                int* __restrict__ tmp,
                                                int* __restrict__ bsum, int n){
  __shared__ int sh[1024];
  int t = threadIdx.x;
  int i = blockIdx.x * 1024 + t;
  sh[t] = (i < n) ? counts[i] : 0;
  __syncthreads();
  for (int o = 1; o < 1024; o <<= 1){
    int x = (t >= o) ? sh[t - o] : 0;
    __syncthreads();
    sh[t] += x;
    __syncthreads();
  }
  if (i < n) tmp[i] = sh[t];
  if (t == 1023) bsum[blockIdx.x] = sh[t];
}

// fused scan2+scan3: each 256-block needs one bbase value (blocks don't
// straddle 1024-windows); the <=98-term prefix is summed serially (uniform).
__global__ void k_scan23(const int* __restrict__ tmp, const int* __restrict__ bsum,
                         int* __restrict__ off, int n){
  int q = blockIdx.x >> 2;      // which scan1 block this 256-chunk lives in
  int bb = 0;
  for (int b = 0; b < q; ++b) bb += bsum[b];
  int i = blockIdx.x * 256 + threadIdx.x;
  if (i < n){
    off[i + 1] = tmp[i] + bb;
    if (i == 0) off[0] = 0;
  }
}

// deterministic scatter, no atomics
__global__ void k_scatter(const int* __restrict__ src, const int* __restrict__ dst,
                          const int* __restrict__ rank, const int* __restrict__ off,
                          int* __restrict__ csr, int e){
  int i = blockIdx.x * 256 + threadIdx.x;
  if (i < e) csr[off[dst[i]] + rank[i]] = src[i];
}

// ---------------- fused GEMM (X @ W) + attention dot epilogue ----------------
// H rows are padded to RS floats: [0,OUTC) = h, [OUTC,OUTC+HEADS) = a_src,
// rest pad. ADST goes to a separate dense table.

template<int OUTC, int HEADS, int CGN, int RPT, int RS>
__global__ __launch_bounds__(256) void k_gemm_att(
    const float* __restrict__ X, const float* __restrict__ W,
    const float* __restrict__ att_s, const float* __restrict__ att_d,
    float* __restrict__ H, float* __restrict__ ADST, int n)
{
  constexpr int K = 128;
  constexpr int KC = 32;
  constexpr int ROWS = (256 / CGN) * RPT;   // 128
  constexpr int CGPH = CGN / HEADS;

  __shared__ float ws[KC][OUTC];
  __shared__ float xs[ROWS][KC + 1];
  __shared__ float pS[ROWS][CGN];
  __shared__ float pD[ROWS][CGN];

  const int tid  = threadIdx.x;
  const int cg   = tid % CGN;
  const int slot = tid / CGN;
  const int row0 = blockIdx.x * ROWS;

  float acc[RPT][16];
  #pragma unroll
  for (int r = 0; r < RPT; ++r)
    #pragma unroll
    for (int j = 0; j < 16; ++j) acc[r][j] = 0.f;

  for (int kc = 0; kc < K; kc += KC){
    {
      const float4* Wv = (const float4*)(W + kc * OUTC);
      for (int idx = tid; idx < KC * OUTC / 4; idx += 256){
        int kk   = idx / (OUTC / 4);
        int rest = idx % (OUTC / 4);
        int bcg  = rest >> 2;
        int j4   = rest & 3;
        float4 v = Wv[idx];
        *(float4*)&ws[kk][bcg * 16 + ((j4 + bcg) & 3) * 4] = v;
      }
    }
    {
      for (int idx = tid; idx < ROWS * (KC / 4); idx += 256){
        int r = idx / (KC / 4);
        int q = idx % (KC / 4);
        int row = row0 + r;
        float4 v = make_float4(0.f, 0.f, 0.f, 0.f);
        if (row < n) v = *(const float4*)&X[(size_t)row * K + kc + q * 4];
        xs[r][q * 4 + 0] = v.x; xs[r][q * 4 + 1] = v.y;
        xs[r][q * 4 + 2] = v.z; xs[r][q * 4 + 3] = v.w;
      }
    }
    __syncthreads();

    #pragma unroll 4
    for (int k = 0; k < KC; ++k){
      float wv[16];
      #pragma unroll
      for (int j4 = 0; j4 < 4; ++j4){
        float4 v = *(const float4*)&ws[k][cg * 16 + ((j4 + cg) & 3) * 4];
        wv[j4 * 4 + 0] = v.x; wv[j4 * 4 + 1] = v.y;
        wv[j4 * 4 + 2] = v.z; wv[j4 * 4 + 3] = v.w;
      }
      #pragma unroll
      for (int r = 0; r < RPT; ++r){
        float xv = xs[slot * RPT + r][k];
        #pragma unroll
        for (int j = 0; j < 16; ++j) acc[r][j] = fmaf(xv, wv[j], acc[r][j]);
      }
    }
    __syncthreads();
  }

  #pragma unroll
  for (int r = 0; r < RPT; ++r){
    int rb  = slot * RPT + r;
    int row = row0 + rb;
    float ps = 0.f, pd = 0.f;
    #pragma unroll
    for (int j = 0; j < 16; ++j){
      int col = cg * 16 + j;
      ps = fmaf(acc[r][j], att_s[col], ps);
      pd = fmaf(acc[r][j], att_d[col], pd);
    }
    pS[rb][cg] = ps; pD[rb][cg] = pd;
    if (row < n){
      #pragma unroll
      for (int j4 = 0; j4 < 4; ++j4){
        *(float4*)&H[(size_t)row * RS + cg * 16 + j4 * 4] =
          make_float4(acc[r][j4*4], acc[r][j4*4+1], acc[r][j4*4+2], acc[r][j4*4+3]);
      }
    }
  }
  __syncthreads();
  for (int rb = tid; rb < ROWS; rb += 256){
    int row = row0 + rb;
    if (row >= n) continue;
    #pragma unroll
    for (int h = 0; h < HEADS; ++h){
      float s = 0.f, d2 = 0.f;
      #pragma unroll
      for (int q = 0; q < CGPH; ++q){ s += pS[rb][h*CGPH + q]; d2 += pD[rb][h*CGPH + q]; }
      H[(size_t)row * RS + OUTC + h] = s;      // a_src embedded in row tail
      ADST[(size_t)row * HEADS + h] = d2;
    }
  }
}

// ---------------- dst-centric aggregation + bias + ELU ----------------
// 2 edge-groups/dst; zero-padded batches of 8: per batch, 8 broadcast csr
// loads, then 8 asrc loads + 8 float4 row gathers in flight (same row
// stream!), then exp + 8x4 fma. w=0 on padded slots -> no tail code.

template<int CH, int HEADS, int RS>
__global__ __launch_bounds__(256) void k_aggregate(
    const float* __restrict__ Hmsg, const float* __restrict__ ADST,
    const int* __restrict__ off, const int* __restrict__ csr,
    const float* __restrict__ bias, float* __restrict__ OUT, int n)
{
  constexpr int CL  = CH / 4;        // channel lanes per group (32 / 16)
  constexpr int LPD = CL * 2;        // lanes per dst (64 / 32)
  constexpr int DPB = 256 / LPD;     // dsts per block (4 / 8)
  constexpr int CPH = CH / HEADS;

  const int tid  = threadIdx.x;
  const int ld   = tid / LPD;
  const int sub  = tid % LPD;
  const int g    = sub / CL;         // edge group 0/1
  const int cl   = sub % CL;
  const int c0   = cl * 4;
  const int h    = c0 / CPH;
  const int d    = blockIdx.x * DPB + ld;
  if (d >= n) return;

  const float adst = ADST[(size_t)d * HEADS + h];

  float wsum = 0.f;
  float4 acc = make_float4(0.f, 0.f, 0.f, 0.f);
  if (g == 0){
    // self loop (asrc from own row tail)
    float t = Hmsg[(size_t)d * RS + CH + h] + adst;
    float w = __expf(fmaxf(t, 0.2f * t));
    float4 hv = *(const float4*)&Hmsg[(size_t)d * RS + c0];
    wsum = w;
    acc = make_float4(w * hv.x, w * hv.y, w * hv.z, w * hv.w);
  }

  const int s0 = off[d], s1 = off[d + 1];
  const int cnt = s1 - s0;
  const int lo = s0 + ((cnt * g) >> 1);
  const int hi = s0 + ((cnt * (g + 1)) >> 1);

  for (int p = lo; p < hi; p += 8){
    int  idx[8];
    bool ok[8];
    #pragma unroll
    for (int j = 0; j < 8; ++j){
      int pos = p + j;                               // csr has +8 slack
      int q = csr[pos];
      ok[j]  = pos < hi;
      idx[j] = ok[j] ? q : 0;
    }
    float  av[8];
    float4 hv[8];
    #pragma unroll
    for (int j = 0; j < 8; ++j) av[j] = Hmsg[(size_t)idx[j] * RS + CH + h];
    #pragma unroll
    for (int j = 0; j < 8; ++j) hv[j] = *(const float4*)&Hmsg[(size_t)idx[j] * RS + c0];
    #pragma unroll
    for (int j = 0; j < 8; ++j){
      float t = av[j] + adst;
      float w = __expf(fmaxf(t, 0.2f * t));
      w = ok[j] ? w : 0.f;
      acc.x = fmaf(w, hv[j].x, acc.x);
      acc.y = fmaf(w, hv[j].y, acc.y);
      acc.z = fmaf(w, hv[j].z, acc.z);
      acc.w = fmaf(w, hv[j].w, acc.w);
      wsum += w;
    }
  }

  // combine the two edge groups
  acc.x += __shfl_xor(acc.x, CL);
  acc.y += __shfl_xor(acc.y, CL);
  acc.z += __shfl_xor(acc.z, CL);
  acc.w += __shfl_xor(acc.w, CL);
  wsum  += __shfl_xor(wsum,  CL);

  if (g == 0){
    const float inv = 1.f / (wsum + 1e-16f);
    float o0 = acc.x * inv + bias[c0 + 0];
    float o1 = acc.y * inv + bias[c0 + 1];
    float o2 = acc.z * inv + bias[c0 + 2];
    float o3 = acc.w * inv + bias[c0 + 3];
    float4 rr;
    rr.x = o0 > 0.f ? o0 : expm1f(o0);
    rr.y = o1 > 0.f ? o1 : expm1f(o1);
    rr.z = o2 > 0.f ? o2 : expm1f(o2);
    rr.w = o3 > 0.f ? o3 : expm1f(o3);
    *(float4*)&OUT[(size_t)d * CH + c0] = rr;   // OUT is dense (stride CH)
  }
}

// ---------------- per-graph mean pool + classifier ----------------

__global__ __launch_bounds__(256) void k_pool(
    const float* __restrict__ H, const int* __restrict__ batch,
    const float* __restrict__ Wc, const float* __restrict__ bc,
    float* __restrict__ out, int n)
{
  int g = blockIdx.x;
  int lo = 0, hi = n;
  while (lo < hi){ int mid = (lo + hi) >> 1; if (batch[mid] < g) lo = mid + 1; else hi = mid; }
  int start = lo;
  lo = start; hi = n;
  while (lo < hi){ int mid = (lo + hi) >> 1; if (batch[mid] < g + 1) lo = mid + 1; else hi = mid; }
  int end = lo;

  int tid = threadIdx.x;
  int c = tid & 63;
  int j = tid >> 6;
  float p = 0.f;
  for (int nn = start + j; nn < end; nn += 4) p += H[(size_t)nn * 64 + c];

  __shared__ float red[4][64];
  __shared__ float mean[64];
  red[j][c] = p;
  __syncthreads();
  if (tid < 64){
    float s = red[0][tid] + red[1][tid] + red[2][tid] + red[3][tid];
    int cnt = end - start;
    mean[tid] = s / (float)(cnt > 1 ? cnt : 1);
  }
  __syncthreads();
  if (tid < 2){
    float o = bc[tid];
    #pragma unroll
    for (int cc = 0; cc < 64; ++cc) o = fmaf(mean[cc], Wc[cc * 2 + tid], o);
    out[g * 2 + tid] = o;
  }
}

// ---------------- launch ----------------

extern "C" void kernel_launch(void* const* d_in, const int* in_sizes, int n_in,
                              void* d_out, int out_size, void* d_ws, size_t ws_size,
                              hipStream_t stream)
{
  const float* x    = (const float*)d_in[0];
  const int*   edge = (const int*)  d_in[1];
  const int*   batch= (const int*)  d_in[2];
  const float* W1   = (const float*)d_in[3];
  const float* as1w = (const float*)d_in[4];
  const float* ad1w = (const float*)d_in[5];
  const float* b1   = (const float*)d_in[6];
  const float* W2   = (const float*)d_in[7];
  const float* as2w = (const float*)d_in[8];
  const float* ad2w = (const float*)d_in[9];
  const float* b2   = (const float*)d_in[10];
  const float* Wc   = (const float*)d_in[11];
  const float* bc   = (const float*)d_in[12];

  const int n = in_sizes[2];          // 100000
  const int e = in_sizes[1] / 2;      // 1600000
  const int* esrc = edge;
  const int* edst = edge + e;

  // row strides (floats): 64B-aligned padded rows with embedded a_src
  constexpr int RS1 = 144;            // 128 h + 4 asrc + 12 pad  (576 B)
  constexpr int RS2 = 80;             // 64 h + 1 asrc + 15 pad   (320 B)

  // workspace layout (fp32 elements)
  float* h1    = (float*)d_ws;                  // n*RS1  (later h2: n*RS2)
  float* h1a   = h1  + (size_t)n * RS1;         // n*128  (later h2a: n*64)
  float* ad1   = h1a + (size_t)n * 128;         // n*4
  float* ad2   = ad1 + (size_t)n * 4;           // n
  int*  counts = (int*)(ad2 + (size_t)n);       // n
  int*  offs   = counts + n;                    // n+1
  int*  tmp    = offs + n + 1;                  // n
  int*  bsum   = tmp + n;                       // 128
  int*  rank   = bsum + 128;                    // e
  int*  csr    = rank + e;                      // e + 8 slack

  const int nb = (n + 1023) / 1024;
  const int eb = (e + 255) / 256;

  // CSR build
  hipMemsetAsync(counts, 0, (size_t)n * 4, stream);
  k_hist   <<<eb, 256, 0, stream>>>(edst, counts, rank, e);
  k_scan1  <<<nb, 1024, 0, stream>>>(counts, tmp, bsum, n);
  k_scan23 <<<(n + 255) / 256, 256, 0, stream>>>(tmp, bsum, offs, n);
  k_scatter<<<eb, 256, 0, stream>>>(esrc, edst, rank, offs, csr, e);

  // conv1
  k_gemm_att<128, 4, 8, 4, RS1><<<(n + 127) / 128, 256, 0, stream>>>(
      x, W1, as1w, ad1w, h1, ad1, n);
  k_aggregate<128, 4, RS1><<<(n + 3) / 4, 256, 0, stream>>>(
      h1, ad1, offs, csr, b1, h1a, n);

  // conv2 (buffer reuse: h2 aliases h1 region, h2a aliases h1a region)
  float* h2  = h1;
  float* h2a = h1a;
  k_gemm_att<64, 1, 4, 2, RS2><<<(n + 127) / 128, 256, 0, stream>>>(
      h1a, W2, as2w, ad2w, h2, ad2, n);
  k_aggregate<64, 1, RS2><<<(n + 7) / 8, 256, 0, stream>>>(
      h2, ad2, offs, csr, b2, h2a, n);

  // pool + classify
  k_pool<<<64, 256, 0, stream>>>(h2a, batch, Wc, bc, (float*)d_out, n);
}

// Round 7
// 560.407 us; speedup vs baseline: 1.1614x; 1.1614x over previous
//
#include <hip/hip_runtime.h>
#include <math.h>

// ---------------------------------------------------------------------------
// GAT 2-layer + mean-pool + classifier.
//  - CSR(dst) built on-device (atomic-free scatter via rank array)
//  - softmax denominators factor out; no segment-max (logits O(1), fp32 safe)
//  - message rows (h tables) stored BF16 (RNE): halves the random-gather
//    payload that pins the aggregate at the ~3.9 TB/s replicated-gather wall.
//    Attention weights stay fp32 (separate dense ASRC/ADST tables, L2-resident)
//    so softmax is exact; only the numerator payload is quantized.
//  - self loops analytic; dst-centric aggregation; no fp atomics
// ---------------------------------------------------------------------------

__device__ __forceinline__ unsigned f2bf_rne(float x){
  unsigned u = __float_as_uint(x);
  return (u + 0x7fffu + ((u >> 16) & 1u)) >> 16;
}
__device__ __forceinline__ unsigned pk_bf2(float a, float b){
  return f2bf_rne(a) | (f2bf_rne(b) << 16);
}
__device__ __forceinline__ void unpack8(uint4 q, float* f){
  f[0] = __uint_as_float(q.x << 16);
  f[1] = __uint_as_float(q.x & 0xffff0000u);
  f[2] = __uint_as_float(q.y << 16);
  f[3] = __uint_as_float(q.y & 0xffff0000u);
  f[4] = __uint_as_float(q.z << 16);
  f[5] = __uint_as_float(q.z & 0xffff0000u);
  f[6] = __uint_as_float(q.w << 16);
  f[7] = __uint_as_float(q.w & 0xffff0000u);
}

// ---------------- CSR build ----------------

__global__ void k_hist(const int* __restrict__ dst, int* __restrict__ counts,
                       int* __restrict__ rank, int e){
  int i = blockIdx.x * 256 + threadIdx.x;
  if (i < e) rank[i] = atomicAdd(&counts[dst[i]], 1);
}

__global__ __launch_bounds__(1024) void k_scan1(const int* __restrict__ counts,
                                                int* __restrict__ tmp,
                                                int* __restrict__ bsum, int n){
  __shared__ int sh[1024];
  int t = threadIdx.x;
  int i = blockIdx.x * 1024 + t;
  sh[t] = (i < n) ? counts[i] : 0;
  __syncthreads();
  for (int o = 1; o < 1024; o <<= 1){
    int x = (t >= o) ? sh[t - o] : 0;
    __syncthreads();
    sh[t] += x;
    __syncthreads();
  }
  if (i < n) tmp[i] = sh[t];
  if (t == 1023) bsum[blockIdx.x] = sh[t];
}

// fused scan2+scan3 (256-blocks never straddle 1024-windows)
__global__ void k_scan23(const int* __restrict__ tmp, const int* __restrict__ bsum,
                         int* __restrict__ off, int n){
  int q = blockIdx.x >> 2;
  int bb = 0;
  for (int b = 0; b < q; ++b) bb += bsum[b];
  int i = blockIdx.x * 256 + threadIdx.x;
  if (i < n){
    off[i + 1] = tmp[i] + bb;
    if (i == 0) off[0] = 0;
  }
}

__global__ void k_scatter(const int* __restrict__ src, const int* __restrict__ dst,
                          const int* __restrict__ rank, const int* __restrict__ off,
                          int* __restrict__ csr, int e){
  int i = blockIdx.x * 256 + threadIdx.x;
  if (i < e) csr[off[dst[i]] + rank[i]] = src[i];
}

// ---------------- fused GEMM (X @ W) + attention dot epilogue ----------------
// H rows stored bf16 (stride OUTC elements); a_src/a_dst to fp32 tables.

template<int OUTC, int HEADS, int CGN, int RPT>
__global__ __launch_bounds__(256) void k_gemm_att(
    const float* __restrict__ X, const float* __restrict__ W,
    const float* __restrict__ att_s, const float* __restrict__ att_d,
    unsigned short* __restrict__ H, float* __restrict__ ASRC,
    float* __restrict__ ADST, int n)
{
  constexpr int K = 128;
  constexpr int KC = 32;
  constexpr int ROWS = (256 / CGN) * RPT;   // 128
  constexpr int CGPH = CGN / HEADS;

  __shared__ float ws[KC][OUTC];
  __shared__ float xs[ROWS][KC + 1];
  __shared__ float pS[ROWS][CGN];
  __shared__ float pD[ROWS][CGN];

  const int tid  = threadIdx.x;
  const int cg   = tid % CGN;
  const int slot = tid / CGN;
  const int row0 = blockIdx.x * ROWS;

  float acc[RPT][16];
  #pragma unroll
  for (int r = 0; r < RPT; ++r)
    #pragma unroll
    for (int j = 0; j < 16; ++j) acc[r][j] = 0.f;

  for (int kc = 0; kc < K; kc += KC){
    {
      const float4* Wv = (const float4*)(W + kc * OUTC);
      for (int idx = tid; idx < KC * OUTC / 4; idx += 256){
        int kk   = idx / (OUTC / 4);
        int rest = idx % (OUTC / 4);
        int bcg  = rest >> 2;
        int j4   = rest & 3;
        float4 v = Wv[idx];
        *(float4*)&ws[kk][bcg * 16 + ((j4 + bcg) & 3) * 4] = v;
      }
    }
    {
      for (int idx = tid; idx < ROWS * (KC / 4); idx += 256){
        int r = idx / (KC / 4);
        int q = idx % (KC / 4);
        int row = row0 + r;
        float4 v = make_float4(0.f, 0.f, 0.f, 0.f);
        if (row < n) v = *(const float4*)&X[(size_t)row * K + kc + q * 4];
        xs[r][q * 4 + 0] = v.x; xs[r][q * 4 + 1] = v.y;
        xs[r][q * 4 + 2] = v.z; xs[r][q * 4 + 3] = v.w;
      }
    }
    __syncthreads();

    #pragma unroll 4
    for (int k = 0; k < KC; ++k){
      float wv[16];
      #pragma unroll
      for (int j4 = 0; j4 < 4; ++j4){
        float4 v = *(const float4*)&ws[k][cg * 16 + ((j4 + cg) & 3) * 4];
        wv[j4 * 4 + 0] = v.x; wv[j4 * 4 + 1] = v.y;
        wv[j4 * 4 + 2] = v.z; wv[j4 * 4 + 3] = v.w;
      }
      #pragma unroll
      for (int r = 0; r < RPT; ++r){
        float xv = xs[slot * RPT + r][k];
        #pragma unroll
        for (int j = 0; j < 16; ++j) acc[r][j] = fmaf(xv, wv[j], acc[r][j]);
      }
    }
    __syncthreads();
  }

  #pragma unroll
  for (int r = 0; r < RPT; ++r){
    int rb  = slot * RPT + r;
    int row = row0 + rb;
    float ps = 0.f, pd = 0.f;
    #pragma unroll
    for (int j = 0; j < 16; ++j){
      int col = cg * 16 + j;
      ps = fmaf(acc[r][j], att_s[col], ps);
      pd = fmaf(acc[r][j], att_d[col], pd);
    }
    pS[rb][cg] = ps; pD[rb][cg] = pd;
    if (row < n){
      unsigned* dst = (unsigned*)(H + (size_t)row * OUTC + cg * 16);
      uint4 q0, q1;
      q0.x = pk_bf2(acc[r][ 0], acc[r][ 1]);
      q0.y = pk_bf2(acc[r][ 2], acc[r][ 3]);
      q0.z = pk_bf2(acc[r][ 4], acc[r][ 5]);
      q0.w = pk_bf2(acc[r][ 6], acc[r][ 7]);
      q1.x = pk_bf2(acc[r][ 8], acc[r][ 9]);
      q1.y = pk_bf2(acc[r][10], acc[r][11]);
      q1.z = pk_bf2(acc[r][12], acc[r][13]);
      q1.w = pk_bf2(acc[r][14], acc[r][15]);
      *(uint4*)(dst + 0) = q0;
      *(uint4*)(dst + 4) = q1;
    }
  }
  __syncthreads();
  for (int rb = tid; rb < ROWS; rb += 256){
    int row = row0 + rb;
    if (row >= n) continue;
    #pragma unroll
    for (int h = 0; h < HEADS; ++h){
      float s = 0.f, d2 = 0.f;
      #pragma unroll
      for (int q = 0; q < CGPH; ++q){ s += pS[rb][h*CGPH + q]; d2 += pD[rb][h*CGPH + q]; }
      ASRC[(size_t)row * HEADS + h] = s;
      ADST[(size_t)row * HEADS + h] = d2;
    }
  }
}

// ---------------- dst-centric aggregation + bias + ELU ----------------
// bf16 rows: each lane covers 8 channels with ONE uint4 gather. 2 edge-groups
// per dst, zero-padded batches of 8 (8 uint4 row gathers + 8 ASRC gathers in
// flight). ASRC table is n*HEADS fp32 (1.6MB / 0.4MB -> L2-resident).

template<int CH, int HEADS>
__global__ __launch_bounds__(256) void k_aggregate(
    const unsigned short* __restrict__ Hmsg, const float* __restrict__ ASRC,
    const float* __restrict__ ADST, const int* __restrict__ off,
    const int* __restrict__ csr, const float* __restrict__ bias,
    float* __restrict__ OUT, int n)
{
  constexpr int CL  = CH / 8;        // lanes per group (16 / 8)
  constexpr int LPD = CL * 2;        // lanes per dst (32 / 16)
  constexpr int DPB = 256 / LPD;     // dsts per block (8 / 16)
  constexpr int CPH = CH / HEADS;    // channels per head (32 / 64)
  constexpr int RQ  = CH / 8;        // uint4 per row

  const int tid  = threadIdx.x;
  const int ld   = tid / LPD;
  const int sub  = tid % LPD;
  const int g    = sub / CL;         // edge group 0/1
  const int cl   = sub % CL;
  const int c0   = cl * 8;
  const int h    = c0 / CPH;
  const int d    = blockIdx.x * DPB + ld;
  if (d >= n) return;

  const uint4* Hv = (const uint4*)Hmsg;
  const float adst = ADST[(size_t)d * HEADS + h];

  float wsum = 0.f;
  float acc[8];
  #pragma unroll
  for (int j = 0; j < 8; ++j) acc[j] = 0.f;

  if (g == 0){
    // self loop
    float t = ASRC[(size_t)d * HEADS + h] + adst;
    float w = __expf(fmaxf(t, 0.2f * t));
    float f[8];
    unpack8(Hv[(size_t)d * RQ + cl], f);
    #pragma unroll
    for (int j = 0; j < 8; ++j) acc[j] = w * f[j];
    wsum = w;
  }

  const int s0 = off[d], s1 = off[d + 1];
  const int cnt = s1 - s0;
  const int lo = s0 + ((cnt * g) >> 1);
  const int hi = s0 + ((cnt * (g + 1)) >> 1);

  for (int p = lo; p < hi; p += 8){
    int  idx[8];
    bool ok[8];
    #pragma unroll
    for (int j = 0; j < 8; ++j){
      int pos = p + j;                          // csr has +8 slack
      int q = csr[pos];
      ok[j]  = pos < hi;
      idx[j] = ok[j] ? q : 0;
    }
    float av[8];
    uint4 hq[8];
    #pragma unroll
    for (int j = 0; j < 8; ++j) av[j] = ASRC[(size_t)idx[j] * HEADS + h];
    #pragma unroll
    for (int j = 0; j < 8; ++j) hq[j] = Hv[(size_t)idx[j] * RQ + cl];
    #pragma unroll
    for (int j = 0; j < 8; ++j){
      float t = av[j] + adst;
      float w = __expf(fmaxf(t, 0.2f * t));
      w = ok[j] ? w : 0.f;
      float f[8];
      unpack8(hq[j], f);
      #pragma unroll
      for (int q = 0; q < 8; ++q) acc[q] = fmaf(w, f[q], acc[q]);
      wsum += w;
    }
  }

  // combine the two edge groups
  #pragma unroll
  for (int j = 0; j < 8; ++j) acc[j] += __shfl_xor(acc[j], CL);
  wsum += __shfl_xor(wsum, CL);

  if (g == 0){
    const float inv = 1.f / (wsum + 1e-16f);
    float4 r0, r1;
    float o[8];
    #pragma unroll
    for (int j = 0; j < 8; ++j){
      float v = acc[j] * inv + bias[c0 + j];
      o[j] = v > 0.f ? v : expm1f(v);
    }
    r0 = make_float4(o[0], o[1], o[2], o[3]);
    r1 = make_float4(o[4], o[5], o[6], o[7]);
    *(float4*)&OUT[(size_t)d * CH + c0 + 0] = r0;
    *(float4*)&OUT[(size_t)d * CH + c0 + 4] = r1;
  }
}

// ---------------- per-graph mean pool + classifier ----------------

__global__ __launch_bounds__(256) void k_pool(
    const float* __restrict__ H, const int* __restrict__ batch,
    const float* __restrict__ Wc, const float* __restrict__ bc,
    float* __restrict__ out, int n)
{
  int g = blockIdx.x;
  int lo = 0, hi = n;
  while (lo < hi){ int mid = (lo + hi) >> 1; if (batch[mid] < g) lo = mid + 1; else hi = mid; }
  int start = lo;
  lo = start; hi = n;
  while (lo < hi){ int mid = (lo + hi) >> 1; if (batch[mid] < g + 1) lo = mid + 1; else hi = mid; }
  int end = lo;

  int tid = threadIdx.x;
  int c = tid & 63;
  int j = tid >> 6;
  float p = 0.f;
  for (int nn = start + j; nn < end; nn += 4) p += H[(size_t)nn * 64 + c];

  __shared__ float red[4][64];
  __shared__ float mean[64];
  red[j][c] = p;
  __syncthreads();
  if (tid < 64){
    float s = red[0][tid] + red[1][tid] + red[2][tid] + red[3][tid];
    int cnt = end - start;
    mean[tid] = s / (float)(cnt > 1 ? cnt : 1);
  }
  __syncthreads();
  if (tid < 2){
    float o = bc[tid];
    #pragma unroll
    for (int cc = 0; cc < 64; ++cc) o = fmaf(mean[cc], Wc[cc * 2 + tid], o);
    out[g * 2 + tid] = o;
  }
}

// ---------------- launch ----------------

extern "C" void kernel_launch(void* const* d_in, const int* in_sizes, int n_in,
                              void* d_out, int out_size, void* d_ws, size_t ws_size,
                              hipStream_t stream)
{
  const float* x    = (const float*)d_in[0];
  const int*   edge = (const int*)  d_in[1];
  const int*   batch= (const int*)  d_in[2];
  const float* W1   = (const float*)d_in[3];
  const float* as1w = (const float*)d_in[4];
  const float* ad1w = (const float*)d_in[5];
  const float* b1   = (const float*)d_in[6];
  const float* W2   = (const float*)d_in[7];
  const float* as2w = (const float*)d_in[8];
  const float* ad2w = (const float*)d_in[9];
  const float* b2   = (const float*)d_in[10];
  const float* Wc   = (const float*)d_in[11];
  const float* bc   = (const float*)d_in[12];

  const int n = in_sizes[2];          // 100000
  const int e = in_sizes[1] / 2;      // 1600000
  const int* esrc = edge;
  const int* edst = edge + e;

  // workspace layout
  float* h1a = (float*)d_ws;                          // n*128 f32 (later h2a n*64)
  unsigned short* h1 = (unsigned short*)(h1a + (size_t)n * 128); // n*128 bf16 (later h2 n*64)
  float* as1 = (float*)(h1 + (size_t)n * 128);        // n*4
  float* ad1 = as1 + (size_t)n * 4;                   // n*4
  float* as2 = ad1 + (size_t)n * 4;                   // n
  float* ad2 = as2 + (size_t)n;                       // n
  int*  counts = (int*)(ad2 + (size_t)n);             // n
  int*  offs   = counts + n;                          // n+1
  int*  tmp    = offs + n + 1;                        // n
  int*  bsum   = tmp + n;                             // 128
  int*  rank   = bsum + 128;                          // e
  int*  csr    = rank + e;                            // e + 8 slack

  const int nb = (n + 1023) / 1024;
  const int eb = (e + 255) / 256;

  // CSR build
  hipMemsetAsync(counts, 0, (size_t)n * 4, stream);
  k_hist   <<<eb, 256, 0, stream>>>(edst, counts, rank, e);
  k_scan1  <<<nb, 1024, 0, stream>>>(counts, tmp, bsum, n);
  k_scan23 <<<(n + 255) / 256, 256, 0, stream>>>(tmp, bsum, offs, n);
  k_scatter<<<eb, 256, 0, stream>>>(esrc, edst, rank, offs, csr, e);

  // conv1
  k_gemm_att<128, 4, 8, 4><<<(n + 127) / 128, 256, 0, stream>>>(
      x, W1, as1w, ad1w, h1, as1, ad1, n);
  k_aggregate<128, 4><<<(n + 7) / 8, 256, 0, stream>>>(
      h1, as1, ad1, offs, csr, b1, h1a, n);

  // conv2 (buffer reuse: h2 aliases h1 region, h2a aliases h1a region)
  unsigned short* h2 = h1;
  float* h2a = h1a;
  k_gemm_att<64, 1, 4, 2><<<(n + 127) / 128, 256, 0, stream>>>(
      h1a, W2, as2w, ad2w, h2, as2, ad2, n);
  k_aggregate<64, 1><<<(n + 15) / 16, 256, 0, stream>>>(
      h2, as2, ad2, offs, csr, b2, h2a, n);

  // pool + classify
  k_pool<<<64, 256, 0, stream>>>(h2a, batch, Wc, bc, (float*)d_out, n);
}

// Round 8
// 493.535 us; speedup vs baseline: 1.3188x; 1.1355x over previous
//
#include <hip/hip_runtime.h>
#include <math.h>

// ---------------------------------------------------------------------------
// GAT 2-layer + mean-pool + classifier.
//  - CSR(dst) built on-device (atomic-free scatter via rank array)
//  - softmax denominators factor out; no segment-max (logits O(1), fp32 safe)
//  - message rows (h tables) stored BF16 (RNE): halves the random-gather
//    payload (agg pinned at the ~3.9 TB/s replicated-gather wall)
//  - pooling: chunk-parallel partial sums + atomicAdd into 64x64 table, then
//    a tiny classify kernel (old 64-block k_pool was launch-shape bound)
// ---------------------------------------------------------------------------

__device__ __forceinline__ unsigned f2bf_rne(float x){
  unsigned u = __float_as_uint(x);
  return (u + 0x7fffu + ((u >> 16) & 1u)) >> 16;
}
__device__ __forceinline__ unsigned pk_bf2(float a, float b){
  return f2bf_rne(a) | (f2bf_rne(b) << 16);
}
__device__ __forceinline__ void unpack8(uint4 q, float* f){
  f[0] = __uint_as_float(q.x << 16);
  f[1] = __uint_as_float(q.x & 0xffff0000u);
  f[2] = __uint_as_float(q.y << 16);
  f[3] = __uint_as_float(q.y & 0xffff0000u);
  f[4] = __uint_as_float(q.z << 16);
  f[5] = __uint_as_float(q.z & 0xffff0000u);
  f[6] = __uint_as_float(q.w << 16);
  f[7] = __uint_as_float(q.w & 0xffff0000u);
}

// ---------------- CSR build ----------------

__global__ void k_hist(const int* __restrict__ dst, int* __restrict__ counts,
                       int* __restrict__ rank, int e){
  int i = blockIdx.x * 256 + threadIdx.x;
  if (i < e) rank[i] = atomicAdd(&counts[dst[i]], 1);
}

__global__ __launch_bounds__(1024) void k_scan1(const int* __restrict__ counts,
                                                int* __restrict__ tmp,
                                                int* __restrict__ bsum, int n){
  __shared__ int sh[1024];
  int t = threadIdx.x;
  int i = blockIdx.x * 1024 + t;
  sh[t] = (i < n) ? counts[i] : 0;
  __syncthreads();
  for (int o = 1; o < 1024; o <<= 1){
    int x = (t >= o) ? sh[t - o] : 0;
    __syncthreads();
    sh[t] += x;
    __syncthreads();
  }
  if (i < n) tmp[i] = sh[t];
  if (t == 1023) bsum[blockIdx.x] = sh[t];
}

// fused scan2+scan3 (256-blocks never straddle 1024-windows)
__global__ void k_scan23(const int* __restrict__ tmp, const int* __restrict__ bsum,
                         int* __restrict__ off, int n){
  int q = blockIdx.x >> 2;
  int bb = 0;
  for (int b = 0; b < q; ++b) bb += bsum[b];
  int i = blockIdx.x * 256 + threadIdx.x;
  if (i < n){
    off[i + 1] = tmp[i] + bb;
    if (i == 0) off[0] = 0;
  }
}

__global__ void k_scatter(const int* __restrict__ src, const int* __restrict__ dst,
                          const int* __restrict__ rank, const int* __restrict__ off,
                          int* __restrict__ csr, int e){
  int i = blockIdx.x * 256 + threadIdx.x;
  if (i < e) csr[off[dst[i]] + rank[i]] = src[i];
}

// ---------------- fused GEMM (X @ W) + attention dot epilogue ----------------
// H rows stored bf16 (stride OUTC elements); a_src/a_dst to fp32 tables.

template<int OUTC, int HEADS, int CGN, int RPT>
__global__ __launch_bounds__(256) void k_gemm_att(
    const float* __restrict__ X, const float* __restrict__ W,
    const float* __restrict__ att_s, const float* __restrict__ att_d,
    unsigned short* __restrict__ H, float* __restrict__ ASRC,
    float* __restrict__ ADST, int n)
{
  constexpr int K = 128;
  constexpr int KC = 32;
  constexpr int ROWS = (256 / CGN) * RPT;   // 128
  constexpr int CGPH = CGN / HEADS;

  __shared__ float ws[KC][OUTC];
  __shared__ float xs[ROWS][KC + 1];
  __shared__ float pS[ROWS][CGN];
  __shared__ float pD[ROWS][CGN];

  const int tid  = threadIdx.x;
  const int cg   = tid % CGN;
  const int slot = tid / CGN;
  const int row0 = blockIdx.x * ROWS;

  float acc[RPT][16];
  #pragma unroll
  for (int r = 0; r < RPT; ++r)
    #pragma unroll
    for (int j = 0; j < 16; ++j) acc[r][j] = 0.f;

  for (int kc = 0; kc < K; kc += KC){
    {
      const float4* Wv = (const float4*)(W + kc * OUTC);
      for (int idx = tid; idx < KC * OUTC / 4; idx += 256){
        int kk   = idx / (OUTC / 4);
        int rest = idx % (OUTC / 4);
        int bcg  = rest >> 2;
        int j4   = rest & 3;
        float4 v = Wv[idx];
        *(float4*)&ws[kk][bcg * 16 + ((j4 + bcg) & 3) * 4] = v;
      }
    }
    {
      for (int idx = tid; idx < ROWS * (KC / 4); idx += 256){
        int r = idx / (KC / 4);
        int q = idx % (KC / 4);
        int row = row0 + r;
        float4 v = make_float4(0.f, 0.f, 0.f, 0.f);
        if (row < n) v = *(const float4*)&X[(size_t)row * K + kc + q * 4];
        xs[r][q * 4 + 0] = v.x; xs[r][q * 4 + 1] = v.y;
        xs[r][q * 4 + 2] = v.z; xs[r][q * 4 + 3] = v.w;
      }
    }
    __syncthreads();

    #pragma unroll 4
    for (int k = 0; k < KC; ++k){
      float wv[16];
      #pragma unroll
      for (int j4 = 0; j4 < 4; ++j4){
        float4 v = *(const float4*)&ws[k][cg * 16 + ((j4 + cg) & 3) * 4];
        wv[j4 * 4 + 0] = v.x; wv[j4 * 4 + 1] = v.y;
        wv[j4 * 4 + 2] = v.z; wv[j4 * 4 + 3] = v.w;
      }
      #pragma unroll
      for (int r = 0; r < RPT; ++r){
        float xv = xs[slot * RPT + r][k];
        #pragma unroll
        for (int j = 0; j < 16; ++j) acc[r][j] = fmaf(xv, wv[j], acc[r][j]);
      }
    }
    __syncthreads();
  }

  #pragma unroll
  for (int r = 0; r < RPT; ++r){
    int rb  = slot * RPT + r;
    int row = row0 + rb;
    float ps = 0.f, pd = 0.f;
    #pragma unroll
    for (int j = 0; j < 16; ++j){
      int col = cg * 16 + j;
      ps = fmaf(acc[r][j], att_s[col], ps);
      pd = fmaf(acc[r][j], att_d[col], pd);
    }
    pS[rb][cg] = ps; pD[rb][cg] = pd;
    if (row < n){
      unsigned* dst = (unsigned*)(H + (size_t)row * OUTC + cg * 16);
      uint4 q0, q1;
      q0.x = pk_bf2(acc[r][ 0], acc[r][ 1]);
      q0.y = pk_bf2(acc[r][ 2], acc[r][ 3]);
      q0.z = pk_bf2(acc[r][ 4], acc[r][ 5]);
      q0.w = pk_bf2(acc[r][ 6], acc[r][ 7]);
      q1.x = pk_bf2(acc[r][ 8], acc[r][ 9]);
      q1.y = pk_bf2(acc[r][10], acc[r][11]);
      q1.z = pk_bf2(acc[r][12], acc[r][13]);
      q1.w = pk_bf2(acc[r][14], acc[r][15]);
      *(uint4*)(dst + 0) = q0;
      *(uint4*)(dst + 4) = q1;
    }
  }
  __syncthreads();
  for (int rb = tid; rb < ROWS; rb += 256){
    int row = row0 + rb;
    if (row >= n) continue;
    #pragma unroll
    for (int h = 0; h < HEADS; ++h){
      float s = 0.f, d2 = 0.f;
      #pragma unroll
      for (int q = 0; q < CGPH; ++q){ s += pS[rb][h*CGPH + q]; d2 += pD[rb][h*CGPH + q]; }
      ASRC[(size_t)row * HEADS + h] = s;
      ADST[(size_t)row * HEADS + h] = d2;
    }
  }
}

// ---------------- dst-centric aggregation + bias + ELU ----------------
// bf16 rows: each lane covers 8 channels with ONE uint4 gather. 2 edge-groups
// per dst, zero-padded batches of 8.

template<int CH, int HEADS>
__global__ __launch_bounds__(256) void k_aggregate(
    const unsigned short* __restrict__ Hmsg, const float* __restrict__ ASRC,
    const float* __restrict__ ADST, const int* __restrict__ off,
    const int* __restrict__ csr, const float* __restrict__ bias,
    float* __restrict__ OUT, int n)
{
  constexpr int CL  = CH / 8;        // lanes per group (16 / 8)
  constexpr int LPD = CL * 2;        // lanes per dst (32 / 16)
  constexpr int DPB = 256 / LPD;     // dsts per block (8 / 16)
  constexpr int CPH = CH / HEADS;    // channels per head (32 / 64)
  constexpr int RQ  = CH / 8;        // uint4 per row

  const int tid  = threadIdx.x;
  const int ld   = tid / LPD;
  const int sub  = tid % LPD;
  const int g    = sub / CL;         // edge group 0/1
  const int cl   = sub % CL;
  const int c0   = cl * 8;
  const int h    = c0 / CPH;
  const int d    = blockIdx.x * DPB + ld;
  if (d >= n) return;

  const uint4* Hv = (const uint4*)Hmsg;
  const float adst = ADST[(size_t)d * HEADS + h];

  float wsum = 0.f;
  float acc[8];
  #pragma unroll
  for (int j = 0; j < 8; ++j) acc[j] = 0.f;

  if (g == 0){
    // self loop
    float t = ASRC[(size_t)d * HEADS + h] + adst;
    float w = __expf(fmaxf(t, 0.2f * t));
    float f[8];
    unpack8(Hv[(size_t)d * RQ + cl], f);
    #pragma unroll
    for (int j = 0; j < 8; ++j) acc[j] = w * f[j];
    wsum = w;
  }

  const int s0 = off[d], s1 = off[d + 1];
  const int cnt = s1 - s0;
  const int lo = s0 + ((cnt * g) >> 1);
  const int hi = s0 + ((cnt * (g + 1)) >> 1);

  for (int p = lo; p < hi; p += 8){
    int  idx[8];
    bool ok[8];
    #pragma unroll
    for (int j = 0; j < 8; ++j){
      int pos = p + j;                          // csr has +8 slack
      int q = csr[pos];
      ok[j]  = pos < hi;
      idx[j] = ok[j] ? q : 0;
    }
    float av[8];
    uint4 hq[8];
    #pragma unroll
    for (int j = 0; j < 8; ++j) av[j] = ASRC[(size_t)idx[j] * HEADS + h];
    #pragma unroll
    for (int j = 0; j < 8; ++j) hq[j] = Hv[(size_t)idx[j] * RQ + cl];
    #pragma unroll
    for (int j = 0; j < 8; ++j){
      float t = av[j] + adst;
      float w = __expf(fmaxf(t, 0.2f * t));
      w = ok[j] ? w : 0.f;
      float f[8];
      unpack8(hq[j], f);
      #pragma unroll
      for (int q = 0; q < 8; ++q) acc[q] = fmaf(w, f[q], acc[q]);
      wsum += w;
    }
  }

  // combine the two edge groups
  #pragma unroll
  for (int j = 0; j < 8; ++j) acc[j] += __shfl_xor(acc[j], CL);
  wsum += __shfl_xor(wsum, CL);

  if (g == 0){
    const float inv = 1.f / (wsum + 1e-16f);
    float o[8];
    #pragma unroll
    for (int j = 0; j < 8; ++j){
      float v = acc[j] * inv + bias[c0 + j];
      o[j] = v > 0.f ? v : expm1f(v);
    }
    *(float4*)&OUT[(size_t)d * CH + c0 + 0] = make_float4(o[0], o[1], o[2], o[3]);
    *(float4*)&OUT[(size_t)d * CH + c0 + 4] = make_float4(o[4], o[5], o[6], o[7]);
  }
}

// ---------------- pooling: chunk-parallel partial sums ----------------
// 256 nodes/block; thread (c = tid&63, slot = tid>>6) accumulates channel c
// over its slot's nodes. batch is sorted, so a chunk spans <=2-3 graphs;
// flush on graph change via fp32 atomicAdd into sums[64][64].

__global__ __launch_bounds__(256) void k_pool_partial(
    const float* __restrict__ H, const int* __restrict__ batch,
    float* __restrict__ sums, int n)
{
  constexpr int CHUNK = 256;
  const int c    = threadIdx.x & 63;
  const int slot = threadIdx.x >> 6;    // 4 node-slots
  const int start = blockIdx.x * CHUNK;
  const int end   = min(start + CHUNK, n);

  float acc = 0.f;
  int cur = -1;
  for (int nn = start + slot; nn < end; nn += 4){
    int g = batch[nn];                  // wave-uniform broadcast load
    if (g != cur){                      // wave-uniform branch
      if (cur >= 0) atomicAdd(&sums[cur * 64 + c], acc);
      acc = 0.f; cur = g;
    }
    acc += H[(size_t)nn * 64 + c];
  }
  if (cur >= 0) atomicAdd(&sums[cur * 64 + c], acc);
}

// classify: 128 threads = (graph g, class cls); counts via binary search
__global__ __launch_bounds__(128) void k_classify(
    const float* __restrict__ sums, const int* __restrict__ batch,
    const float* __restrict__ Wc, const float* __restrict__ bc,
    float* __restrict__ out, int n)
{
  int t = threadIdx.x;
  if (t >= 128) return;
  int g = t >> 1, cls = t & 1;
  int lo = 0, hi = n;
  while (lo < hi){ int m = (lo + hi) >> 1; if (batch[m] < g) lo = m + 1; else hi = m; }
  int s = lo;
  lo = s; hi = n;
  while (lo < hi){ int m = (lo + hi) >> 1; if (batch[m] < g + 1) lo = m + 1; else hi = m; }
  int cnt = lo - s;
  float inv = 1.f / (float)(cnt > 1 ? cnt : 1);
  float dot = 0.f;
  #pragma unroll
  for (int c = 0; c < 64; ++c) dot = fmaf(sums[g * 64 + c], Wc[c * 2 + cls], dot);
  out[g * 2 + cls] = dot * inv + bc[cls];
}

// ---------------- launch ----------------

extern "C" void kernel_launch(void* const* d_in, const int* in_sizes, int n_in,
                              void* d_out, int out_size, void* d_ws, size_t ws_size,
                              hipStream_t stream)
{
  const float* x    = (const float*)d_in[0];
  const int*   edge = (const int*)  d_in[1];
  const int*   batch= (const int*)  d_in[2];
  const float* W1   = (const float*)d_in[3];
  const float* as1w = (const float*)d_in[4];
  const float* ad1w = (const float*)d_in[5];
  const float* b1   = (const float*)d_in[6];
  const float* W2   = (const float*)d_in[7];
  const float* as2w = (const float*)d_in[8];
  const float* ad2w = (const float*)d_in[9];
  const float* b2   = (const float*)d_in[10];
  const float* Wc   = (const float*)d_in[11];
  const float* bc   = (const float*)d_in[12];

  const int n = in_sizes[2];          // 100000
  const int e = in_sizes[1] / 2;      // 1600000
  const int* esrc = edge;
  const int* edst = edge + e;

  // workspace layout
  float* h1a = (float*)d_ws;                          // n*128 f32 (later h2a n*64)
  unsigned short* h1 = (unsigned short*)(h1a + (size_t)n * 128); // n*128 bf16
  float* as1 = (float*)(h1 + (size_t)n * 128);        // n*4
  float* ad1 = as1 + (size_t)n * 4;                   // n*4
  float* as2 = ad1 + (size_t)n * 4;                   // n
  float* ad2 = as2 + (size_t)n;                       // n
  float* sums = ad2 + (size_t)n;                      // 64*64
  int*  counts = (int*)(sums + 64 * 64);              // n
  int*  offs   = counts + n;                          // n+1
  int*  tmp    = offs + n + 1;                        // n
  int*  bsum   = tmp + n;                             // 128
  int*  rank   = bsum + 128;                          // e
  int*  csr    = rank + e;                            // e + 8 slack

  const int nb = (n + 1023) / 1024;
  const int eb = (e + 255) / 256;

  // CSR build
  hipMemsetAsync(counts, 0, (size_t)n * 4, stream);
  hipMemsetAsync(sums, 0, 64 * 64 * 4, stream);
  k_hist   <<<eb, 256, 0, stream>>>(edst, counts, rank, e);
  k_scan1  <<<nb, 1024, 0, stream>>>(counts, tmp, bsum, n);
  k_scan23 <<<(n + 255) / 256, 256, 0, stream>>>(tmp, bsum, offs, n);
  k_scatter<<<eb, 256, 0, stream>>>(esrc, edst, rank, offs, csr, e);

  // conv1
  k_gemm_att<128, 4, 8, 4><<<(n + 127) / 128, 256, 0, stream>>>(
      x, W1, as1w, ad1w, h1, as1, ad1, n);
  k_aggregate<128, 4><<<(n + 7) / 8, 256, 0, stream>>>(
      h1, as1, ad1, offs, csr, b1, h1a, n);

  // conv2 (buffer reuse: h2 aliases h1 region, h2a aliases h1a region)
  unsigned short* h2 = h1;
  float* h2a = h1a;
  k_gemm_att<64, 1, 4, 2><<<(n + 127) / 128, 256, 0, stream>>>(
      h1a, W2, as2w, ad2w, h2, as2, ad2, n);
  k_aggregate<64, 1><<<(n + 15) / 16, 256, 0, stream>>>(
      h2, as2, ad2, offs, csr, b2, h2a, n);

  // pool + classify
  k_pool_partial<<<(n + 255) / 256, 256, 0, stream>>>(h2a, batch, sums, n);
  k_classify<<<1, 128, 0, stream>>>(sums, batch, Wc, bc, (float*)d_out, n);
}

// Round 9
// 489.628 us; speedup vs baseline: 1.3293x; 1.0080x over previous
//
#include <hip/hip_runtime.h>
#include <math.h>

// ---------------------------------------------------------------------------
// GAT 2-layer + mean-pool + classifier.
//  - CSR(dst) built on-device (atomic-free scatter via rank array)
//  - softmax denominators factor out; no segment-max (logits O(1), fp32 safe)
//  - message rows (h tables) stored BF16 (RNE): halves the random-gather
//    payload; traffic at the 8-XCD replication floor
//  - aggregation: PERSISTENT grid (2048 blocks = 8192 waves fill every
//    wave-slot) + grid-stride over dsts -> no wave churn (R8: occupancy 38%)
//  - pooling: chunk-parallel partial sums + atomicAdd, tiny classify kernel
// ---------------------------------------------------------------------------

__device__ __forceinline__ unsigned f2bf_rne(float x){
  unsigned u = __float_as_uint(x);
  return (u + 0x7fffu + ((u >> 16) & 1u)) >> 16;
}
__device__ __forceinline__ unsigned pk_bf2(float a, float b){
  return f2bf_rne(a) | (f2bf_rne(b) << 16);
}
__device__ __forceinline__ void unpack8(uint4 q, float* f){
  f[0] = __uint_as_float(q.x << 16);
  f[1] = __uint_as_float(q.x & 0xffff0000u);
  f[2] = __uint_as_float(q.y << 16);
  f[3] = __uint_as_float(q.y & 0xffff0000u);
  f[4] = __uint_as_float(q.z << 16);
  f[5] = __uint_as_float(q.z & 0xffff0000u);
  f[6] = __uint_as_float(q.w << 16);
  f[7] = __uint_as_float(q.w & 0xffff0000u);
}

// ---------------- CSR build ----------------

__global__ void k_hist(const int* __restrict__ dst, int* __restrict__ counts,
                       int* __restrict__ rank, int e){
  int i = blockIdx.x * 256 + threadIdx.x;
  if (i < e) rank[i] = atomicAdd(&counts[dst[i]], 1);
}

__global__ __launch_bounds__(1024) void k_scan1(const int* __restrict__ counts,
                                                int* __restrict__ tmp,
                                                int* __restrict__ bsum, int n){
  __shared__ int sh[1024];
  int t = threadIdx.x;
  int i = blockIdx.x * 1024 + t;
  sh[t] = (i < n) ? counts[i] : 0;
  __syncthreads();
  for (int o = 1; o < 1024; o <<= 1){
    int x = (t >= o) ? sh[t - o] : 0;
    __syncthreads();
    sh[t] += x;
    __syncthreads();
  }
  if (i < n) tmp[i] = sh[t];
  if (t == 1023) bsum[blockIdx.x] = sh[t];
}

// fused scan2+scan3 (256-blocks never straddle 1024-windows)
__global__ void k_scan23(const int* __restrict__ tmp, const int* __restrict__ bsum,
                         int* __restrict__ off, int n){
  int q = blockIdx.x >> 2;
  int bb = 0;
  for (int b = 0; b < q; ++b) bb += bsum[b];
  int i = blockIdx.x * 256 + threadIdx.x;
  if (i < n){
    off[i + 1] = tmp[i] + bb;
    if (i == 0) off[0] = 0;
  }
}

__global__ void k_scatter(const int* __restrict__ src, const int* __restrict__ dst,
                          const int* __restrict__ rank, const int* __restrict__ off,
                          int* __restrict__ csr, int e){
  int i = blockIdx.x * 256 + threadIdx.x;
  if (i < e) csr[off[dst[i]] + rank[i]] = src[i];
}

// ---------------- fused GEMM (X @ W) + attention dot epilogue ----------------
// H rows stored bf16 (stride OUTC elements); a_src/a_dst to fp32 tables.

template<int OUTC, int HEADS, int CGN, int RPT>
__global__ __launch_bounds__(256) void k_gemm_att(
    const float* __restrict__ X, const float* __restrict__ W,
    const float* __restrict__ att_s, const float* __restrict__ att_d,
    unsigned short* __restrict__ H, float* __restrict__ ASRC,
    float* __restrict__ ADST, int n)
{
  constexpr int K = 128;
  constexpr int KC = 32;
  constexpr int ROWS = (256 / CGN) * RPT;   // 128
  constexpr int CGPH = CGN / HEADS;

  __shared__ float ws[KC][OUTC];
  __shared__ float xs[ROWS][KC + 1];
  __shared__ float pS[ROWS][CGN];
  __shared__ float pD[ROWS][CGN];

  const int tid  = threadIdx.x;
  const int cg   = tid % CGN;
  const int slot = tid / CGN;
  const int row0 = blockIdx.x * ROWS;

  float acc[RPT][16];
  #pragma unroll
  for (int r = 0; r < RPT; ++r)
    #pragma unroll
    for (int j = 0; j < 16; ++j) acc[r][j] = 0.f;

  for (int kc = 0; kc < K; kc += KC){
    {
      const float4* Wv = (const float4*)(W + kc * OUTC);
      for (int idx = tid; idx < KC * OUTC / 4; idx += 256){
        int kk   = idx / (OUTC / 4);
        int rest = idx % (OUTC / 4);
        int bcg  = rest >> 2;
        int j4   = rest & 3;
        float4 v = Wv[idx];
        *(float4*)&ws[kk][bcg * 16 + ((j4 + bcg) & 3) * 4] = v;
      }
    }
    {
      for (int idx = tid; idx < ROWS * (KC / 4); idx += 256){
        int r = idx / (KC / 4);
        int q = idx % (KC / 4);
        int row = row0 + r;
        float4 v = make_float4(0.f, 0.f, 0.f, 0.f);
        if (row < n) v = *(const float4*)&X[(size_t)row * K + kc + q * 4];
        xs[r][q * 4 + 0] = v.x; xs[r][q * 4 + 1] = v.y;
        xs[r][q * 4 + 2] = v.z; xs[r][q * 4 + 3] = v.w;
      }
    }
    __syncthreads();

    #pragma unroll 4
    for (int k = 0; k < KC; ++k){
      float wv[16];
      #pragma unroll
      for (int j4 = 0; j4 < 4; ++j4){
        float4 v = *(const float4*)&ws[k][cg * 16 + ((j4 + cg) & 3) * 4];
        wv[j4 * 4 + 0] = v.x; wv[j4 * 4 + 1] = v.y;
        wv[j4 * 4 + 2] = v.z; wv[j4 * 4 + 3] = v.w;
      }
      #pragma unroll
      for (int r = 0; r < RPT; ++r){
        float xv = xs[slot * RPT + r][k];
        #pragma unroll
        for (int j = 0; j < 16; ++j) acc[r][j] = fmaf(xv, wv[j], acc[r][j]);
      }
    }
    __syncthreads();
  }

  #pragma unroll
  for (int r = 0; r < RPT; ++r){
    int rb  = slot * RPT + r;
    int row = row0 + rb;
    float ps = 0.f, pd = 0.f;
    #pragma unroll
    for (int j = 0; j < 16; ++j){
      int col = cg * 16 + j;
      ps = fmaf(acc[r][j], att_s[col], ps);
      pd = fmaf(acc[r][j], att_d[col], pd);
    }
    pS[rb][cg] = ps; pD[rb][cg] = pd;
    if (row < n){
      unsigned* dst = (unsigned*)(H + (size_t)row * OUTC + cg * 16);
      uint4 q0, q1;
      q0.x = pk_bf2(acc[r][ 0], acc[r][ 1]);
      q0.y = pk_bf2(acc[r][ 2], acc[r][ 3]);
      q0.z = pk_bf2(acc[r][ 4], acc[r][ 5]);
      q0.w = pk_bf2(acc[r][ 6], acc[r][ 7]);
      q1.x = pk_bf2(acc[r][ 8], acc[r][ 9]);
      q1.y = pk_bf2(acc[r][10], acc[r][11]);
      q1.z = pk_bf2(acc[r][12], acc[r][13]);
      q1.w = pk_bf2(acc[r][14], acc[r][15]);
      *(uint4*)(dst + 0) = q0;
      *(uint4*)(dst + 4) = q1;
    }
  }
  __syncthreads();
  for (int rb = tid; rb < ROWS; rb += 256){
    int row = row0 + rb;
    if (row >= n) continue;
    #pragma unroll
    for (int h = 0; h < HEADS; ++h){
      float s = 0.f, d2 = 0.f;
      #pragma unroll
      for (int q = 0; q < CGPH; ++q){ s += pS[rb][h*CGPH + q]; d2 += pD[rb][h*CGPH + q]; }
      ASRC[(size_t)row * HEADS + h] = s;
      ADST[(size_t)row * HEADS + h] = d2;
    }
  }
}

// ---------------- dst-centric aggregation + bias + ELU ----------------
// bf16 rows, lane covers 8 channels (one uint4 gather). 2 edge-groups/dst,
// zero-padded batches of 8. PERSISTENT: grid-stride over virtual dst-blocks.

template<int CH, int HEADS>
__global__ __launch_bounds__(256) void k_aggregate(
    const unsigned short* __restrict__ Hmsg, const float* __restrict__ ASRC,
    const float* __restrict__ ADST, const int* __restrict__ off,
    const int* __restrict__ csr, const float* __restrict__ bias,
    float* __restrict__ OUT, int n)
{
  constexpr int CL  = CH / 8;        // lanes per group (16 / 8)
  constexpr int LPD = CL * 2;        // lanes per dst (32 / 16)
  constexpr int DPB = 256 / LPD;     // dsts per block (8 / 16)
  constexpr int CPH = CH / HEADS;    // channels per head (32 / 64)
  constexpr int RQ  = CH / 8;        // uint4 per row

  const int tid  = threadIdx.x;
  const int ld   = tid / LPD;
  const int sub  = tid % LPD;
  const int g    = sub / CL;         // edge group 0/1
  const int cl   = sub % CL;
  const int c0   = cl * 8;
  const int h    = c0 / CPH;

  const uint4* Hv = (const uint4*)Hmsg;
  const int nvb = (n + DPB - 1) / DPB;

  for (int vb = blockIdx.x; vb < nvb; vb += gridDim.x){
    const int d = vb * DPB + ld;
    if (d >= n) continue;

    const float adst = ADST[(size_t)d * HEADS + h];

    float wsum = 0.f;
    float acc[8];
    #pragma unroll
    for (int j = 0; j < 8; ++j) acc[j] = 0.f;

    if (g == 0){
      // self loop
      float t = ASRC[(size_t)d * HEADS + h] + adst;
      float w = __expf(fmaxf(t, 0.2f * t));
      float f[8];
      unpack8(Hv[(size_t)d * RQ + cl], f);
      #pragma unroll
      for (int j = 0; j < 8; ++j) acc[j] = w * f[j];
      wsum = w;
    }

    const int s0 = off[d], s1 = off[d + 1];
    const int cnt = s1 - s0;
    const int lo = s0 + ((cnt * g) >> 1);
    const int hi = s0 + ((cnt * (g + 1)) >> 1);

    for (int p = lo; p < hi; p += 8){
      int  idx[8];
      bool ok[8];
      #pragma unroll
      for (int j = 0; j < 8; ++j){
        int pos = p + j;                          // csr has +8 slack
        int q = csr[pos];
        ok[j]  = pos < hi;
        idx[j] = ok[j] ? q : 0;
      }
      float av[8];
      uint4 hq[8];
      #pragma unroll
      for (int j = 0; j < 8; ++j) av[j] = ASRC[(size_t)idx[j] * HEADS + h];
      #pragma unroll
      for (int j = 0; j < 8; ++j) hq[j] = Hv[(size_t)idx[j] * RQ + cl];
      #pragma unroll
      for (int j = 0; j < 8; ++j){
        float t = av[j] + adst;
        float w = __expf(fmaxf(t, 0.2f * t));
        w = ok[j] ? w : 0.f;
        float f[8];
        unpack8(hq[j], f);
        #pragma unroll
        for (int q = 0; q < 8; ++q) acc[q] = fmaf(w, f[q], acc[q]);
        wsum += w;
      }
    }

    // combine the two edge groups
    #pragma unroll
    for (int j = 0; j < 8; ++j) acc[j] += __shfl_xor(acc[j], CL);
    wsum += __shfl_xor(wsum, CL);

    if (g == 0){
      const float inv = 1.f / (wsum + 1e-16f);
      float o[8];
      #pragma unroll
      for (int j = 0; j < 8; ++j){
        float v = acc[j] * inv + bias[c0 + j];
        o[j] = v > 0.f ? v : expm1f(v);
      }
      *(float4*)&OUT[(size_t)d * CH + c0 + 0] = make_float4(o[0], o[1], o[2], o[3]);
      *(float4*)&OUT[(size_t)d * CH + c0 + 4] = make_float4(o[4], o[5], o[6], o[7]);
    }
  }
}

// ---------------- pooling: chunk-parallel partial sums ----------------

__global__ __launch_bounds__(256) void k_pool_partial(
    const float* __restrict__ H, const int* __restrict__ batch,
    float* __restrict__ sums, int n)
{
  constexpr int CHUNK = 256;
  const int c    = threadIdx.x & 63;
  const int slot = threadIdx.x >> 6;    // 4 node-slots
  const int start = blockIdx.x * CHUNK;
  const int end   = min(start + CHUNK, n);

  float acc = 0.f;
  int cur = -1;
  for (int nn = start + slot; nn < end; nn += 4){
    int g = batch[nn];                  // wave-uniform broadcast load
    if (g != cur){                      // wave-uniform branch
      if (cur >= 0) atomicAdd(&sums[cur * 64 + c], acc);
      acc = 0.f; cur = g;
    }
    acc += H[(size_t)nn * 64 + c];
  }
  if (cur >= 0) atomicAdd(&sums[cur * 64 + c], acc);
}

// classify: 128 threads = (graph g, class cls); counts via binary search
__global__ __launch_bounds__(128) void k_classify(
    const float* __restrict__ sums, const int* __restrict__ batch,
    const float* __restrict__ Wc, const float* __restrict__ bc,
    float* __restrict__ out, int n)
{
  int t = threadIdx.x;
  if (t >= 128) return;
  int g = t >> 1, cls = t & 1;
  int lo = 0, hi = n;
  while (lo < hi){ int m = (lo + hi) >> 1; if (batch[m] < g) lo = m + 1; else hi = m; }
  int s = lo;
  lo = s; hi = n;
  while (lo < hi){ int m = (lo + hi) >> 1; if (batch[m] < g + 1) lo = m + 1; else hi = m; }
  int cnt = lo - s;
  float inv = 1.f / (float)(cnt > 1 ? cnt : 1);
  float dot = 0.f;
  #pragma unroll
  for (int c = 0; c < 64; ++c) dot = fmaf(sums[g * 64 + c], Wc[c * 2 + cls], dot);
  out[g * 2 + cls] = dot * inv + bc[cls];
}

// ---------------- launch ----------------

extern "C" void kernel_launch(void* const* d_in, const int* in_sizes, int n_in,
                              void* d_out, int out_size, void* d_ws, size_t ws_size,
                              hipStream_t stream)
{
  const float* x    = (const float*)d_in[0];
  const int*   edge = (const int*)  d_in[1];
  const int*   batch= (const int*)  d_in[2];
  const float* W1   = (const float*)d_in[3];
  const float* as1w = (const float*)d_in[4];
  const float* ad1w = (const float*)d_in[5];
  const float* b1   = (const float*)d_in[6];
  const float* W2   = (const float*)d_in[7];
  const float* as2w = (const float*)d_in[8];
  const float* ad2w = (const float*)d_in[9];
  const float* b2   = (const float*)d_in[10];
  const float* Wc   = (const float*)d_in[11];
  const float* bc   = (const float*)d_in[12];

  const int n = in_sizes[2];          // 100000
  const int e = in_sizes[1] / 2;      // 1600000
  const int* esrc = edge;
  const int* edst = edge + e;

  // workspace layout
  float* h1a = (float*)d_ws;                          // n*128 f32 (later h2a n*64)
  unsigned short* h1 = (unsigned short*)(h1a + (size_t)n * 128); // n*128 bf16
  float* as1 = (float*)(h1 + (size_t)n * 128);        // n*4
  float* ad1 = as1 + (size_t)n * 4;                   // n*4
  float* as2 = ad1 + (size_t)n * 4;                   // n
  float* ad2 = as2 + (size_t)n;                       // n
  float* sums = ad2 + (size_t)n;                      // 64*64
  int*  counts = (int*)(sums + 64 * 64);              // n
  int*  offs   = counts + n;                          // n+1
  int*  tmp    = offs + n + 1;                        // n
  int*  bsum   = tmp + n;                             // 128
  int*  rank   = bsum + 128;                          // e
  int*  csr    = rank + e;                            // e + 8 slack

  const int nb = (n + 1023) / 1024;
  const int eb = (e + 255) / 256;

  // CSR build
  hipMemsetAsync(counts, 0, (size_t)n * 4, stream);
  hipMemsetAsync(sums, 0, 64 * 64 * 4, stream);
  k_hist   <<<eb, 256, 0, stream>>>(edst, counts, rank, e);
  k_scan1  <<<nb, 1024, 0, stream>>>(counts, tmp, bsum, n);
  k_scan23 <<<(n + 255) / 256, 256, 0, stream>>>(tmp, bsum, offs, n);
  k_scatter<<<eb, 256, 0, stream>>>(esrc, edst, rank, offs, csr, e);

  // conv1
  k_gemm_att<128, 4, 8, 4><<<(n + 127) / 128, 256, 0, stream>>>(
      x, W1, as1w, ad1w, h1, as1, ad1, n);
  k_aggregate<128, 4><<<2048, 256, 0, stream>>>(
      h1, as1, ad1, offs, csr, b1, h1a, n);

  // conv2 (buffer reuse: h2 aliases h1 region, h2a aliases h1a region)
  unsigned short* h2 = h1;
  float* h2a = h1a;
  k_gemm_att<64, 1, 4, 2><<<(n + 127) / 128, 256, 0, stream>>>(
      h1a, W2, as2w, ad2w, h2, as2, ad2, n);
  k_aggregate<64, 1><<<2048, 256, 0, stream>>>(
      h2, as2, ad2, offs, csr, b2, h2a, n);

  // pool + classify
  k_pool_partial<<<(n + 255) / 256, 256, 0, stream>>>(h2a, batch, sums, n);
  k_classify<<<1, 128, 0, stream>>>(sums, batch, Wc, bc, (float*)d_out, n);
}

// Round 10
// 484.114 us; speedup vs baseline: 1.3444x; 1.0114x over previous
//
#include <hip/hip_runtime.h>
#include <math.h>

// ---------------------------------------------------------------------------
// GAT 2-layer + mean-pool + classifier.
//  - CSR(dst) built on-device (atomic-free scatter via rank array)
//  - softmax denominators factor out; no segment-max (logits O(1), fp32 safe)
//  - message tables bf16; h1a (layer-2 input) also bf16
//  - aggregation FROZEN at the measured replicated-gather floor (~100 us L1)
//  - GEMM: transposed x-tile in LDS (conflict-free b128 reads), shfl-reduced
//    attention dots (no pS/pD LDS, one less barrier)
// ---------------------------------------------------------------------------

__device__ __forceinline__ unsigned f2bf_rne(float x){
  unsigned u = __float_as_uint(x);
  return (u + 0x7fffu + ((u >> 16) & 1u)) >> 16;
}
__device__ __forceinline__ unsigned pk_bf2(float a, float b){
  return f2bf_rne(a) | (f2bf_rne(b) << 16);
}
__device__ __forceinline__ void unpack8(uint4 q, float* f){
  f[0] = __uint_as_float(q.x << 16);
  f[1] = __uint_as_float(q.x & 0xffff0000u);
  f[2] = __uint_as_float(q.y << 16);
  f[3] = __uint_as_float(q.y & 0xffff0000u);
  f[4] = __uint_as_float(q.z << 16);
  f[5] = __uint_as_float(q.z & 0xffff0000u);
  f[6] = __uint_as_float(q.w << 16);
  f[7] = __uint_as_float(q.w & 0xffff0000u);
}

// ---------------- CSR build ----------------

__global__ void k_hist(const int* __restrict__ dst, int* __restrict__ counts,
                       int* __restrict__ rank, int e){
  int i = blockIdx.x * 256 + threadIdx.x;
  if (i < e) rank[i] = atomicAdd(&counts[dst[i]], 1);
}

__global__ __launch_bounds__(1024) void k_scan1(const int* __restrict__ counts,
                                                int* __restrict__ tmp,
                                                int* __restrict__ bsum, int n){
  __shared__ int sh[1024];
  int t = threadIdx.x;
  int i = blockIdx.x * 1024 + t;
  sh[t] = (i < n) ? counts[i] : 0;
  __syncthreads();
  for (int o = 1; o < 1024; o <<= 1){
    int x = (t >= o) ? sh[t - o] : 0;
    __syncthreads();
    sh[t] += x;
    __syncthreads();
  }
  if (i < n) tmp[i] = sh[t];
  if (t == 1023) bsum[blockIdx.x] = sh[t];
}

__global__ void k_scan23(const int* __restrict__ tmp, const int* __restrict__ bsum,
                         int* __restrict__ off, int n){
  int q = blockIdx.x >> 2;
  int bb = 0;
  for (int b = 0; b < q; ++b) bb += bsum[b];
  int i = blockIdx.x * 256 + threadIdx.x;
  if (i < n){
    off[i + 1] = tmp[i] + bb;
    if (i == 0) off[0] = 0;
  }
}

__global__ void k_scatter(const int* __restrict__ src, const int* __restrict__ dst,
                          const int* __restrict__ rank, const int* __restrict__ off,
                          int* __restrict__ csr, int e){
  int i = blockIdx.x * 256 + threadIdx.x;
  if (i < e) csr[off[dst[i]] + rank[i]] = src[i];
}

// ---------------- fused GEMM (X @ W) + attention dot epilogue ----------------
// xs stored TRANSPOSED [KC][ROWS+5] (odd word stride -> 2-way/free banks);
// k-loop reads 1 vector load per thread covering its RPT rows.
// Attention dots reduced via shfl_xor across the CGN consecutive lanes.

template<int OUTC, int HEADS, int CGN, int RPT, bool XBF16, typename XT>
__global__ __launch_bounds__(256) void k_gemm_att(
    const XT* __restrict__ X, const float* __restrict__ W,
    const float* __restrict__ att_s, const float* __restrict__ att_d,
    unsigned short* __restrict__ H, float* __restrict__ ASRC,
    float* __restrict__ ADST, int n)
{
  constexpr int K = 128;
  constexpr int KC = 32;
  constexpr int ROWS = (256 / CGN) * RPT;   // 128
  constexpr int XST = ROWS + 5;             // 133 (odd) -> conflict-light

  __shared__ float ws[KC][OUTC];
  __shared__ float xs[KC][XST];

  const int tid  = threadIdx.x;
  const int cg   = tid % CGN;
  const int slot = tid / CGN;
  const int row0 = blockIdx.x * ROWS;

  float acc[RPT][16];
  #pragma unroll
  for (int r = 0; r < RPT; ++r)
    #pragma unroll
    for (int j = 0; j < 16; ++j) acc[r][j] = 0.f;

  for (int kc = 0; kc < K; kc += KC){
    // stage W chunk (swizzled float4 rotation within 16-col groups)
    {
      const float4* Wv = (const float4*)(W + kc * OUTC);
      for (int idx = tid; idx < KC * OUTC / 4; idx += 256){
        int kk   = idx / (OUTC / 4);
        int rest = idx % (OUTC / 4);
        int bcg  = rest >> 2;
        int j4   = rest & 3;
        float4 v = Wv[idx];
        *(float4*)&ws[kk][bcg * 16 + ((j4 + bcg) & 3) * 4] = v;
      }
    }
    // stage X chunk transposed
    if (XBF16){
      // bf16 rows: one uint4 = 8 k-values
      for (int idx = tid; idx < ROWS * (KC / 8); idx += 256){
        int r = idx / (KC / 8);
        int q = idx % (KC / 8);
        int row = row0 + r;
        uint4 v = make_uint4(0, 0, 0, 0);
        if (row < n) v = *(const uint4*)((const unsigned short*)X + (size_t)row * K + kc + q * 8);
        float f[8];
        unpack8(v, f);
        #pragma unroll
        for (int j = 0; j < 8; ++j) xs[q * 8 + j][r] = f[j];
      }
    } else {
      for (int idx = tid; idx < ROWS * (KC / 4); idx += 256){
        int r = idx / (KC / 4);
        int q = idx % (KC / 4);
        int row = row0 + r;
        float4 v = make_float4(0.f, 0.f, 0.f, 0.f);
        if (row < n) v = *(const float4*)((const float*)X + (size_t)row * K + kc + q * 4);
        xs[q * 4 + 0][r] = v.x; xs[q * 4 + 1][r] = v.y;
        xs[q * 4 + 2][r] = v.z; xs[q * 4 + 3][r] = v.w;
      }
    }
    __syncthreads();

    #pragma unroll 4
    for (int k = 0; k < KC; ++k){
      float wv[16];
      #pragma unroll
      for (int j4 = 0; j4 < 4; ++j4){
        float4 v = *(const float4*)&ws[k][cg * 16 + ((j4 + cg) & 3) * 4];
        wv[j4 * 4 + 0] = v.x; wv[j4 * 4 + 1] = v.y;
        wv[j4 * 4 + 2] = v.z; wv[j4 * 4 + 3] = v.w;
      }
      float xv[RPT];
      if (RPT == 4){
        float4 v = *(const float4*)&xs[k][slot * 4];
        xv[0] = v.x; xv[1] = v.y; xv[2] = v.z; xv[RPT - 1] = v.w;
      } else {
        float2 v = *(const float2*)&xs[k][slot * 2];
        xv[0] = v.x; xv[RPT - 1] = v.y;
      }
      #pragma unroll
      for (int r = 0; r < RPT; ++r){
        #pragma unroll
        for (int j = 0; j < 16; ++j) acc[r][j] = fmaf(xv[r], wv[j], acc[r][j]);
      }
    }
    __syncthreads();
  }

  // epilogue: bf16 H write + shfl-reduced attention dots
  #pragma unroll
  for (int r = 0; r < RPT; ++r){
    int row = row0 + slot * RPT + r;
    float ps = 0.f, pd = 0.f;
    #pragma unroll
    for (int j = 0; j < 16; ++j){
      int col = cg * 16 + j;
      ps = fmaf(acc[r][j], att_s[col], ps);
      pd = fmaf(acc[r][j], att_d[col], pd);
    }
    // reduce across the CGN consecutive lanes down to per-head sums
    if (HEADS == 4){
      // CGN=8, head = cg>>1: combine cg pairs
      ps += __shfl_xor(ps, 1);
      pd += __shfl_xor(pd, 1);
    } else {
      // CGN=4, single head: full reduction
      ps += __shfl_xor(ps, 1); ps += __shfl_xor(ps, 2);
      pd += __shfl_xor(pd, 1); pd += __shfl_xor(pd, 2);
    }
    if (row < n){
      unsigned* dst = (unsigned*)(H + (size_t)row * OUTC + cg * 16);
      uint4 q0, q1;
      q0.x = pk_bf2(acc[r][ 0], acc[r][ 1]);
      q0.y = pk_bf2(acc[r][ 2], acc[r][ 3]);
      q0.z = pk_bf2(acc[r][ 4], acc[r][ 5]);
      q0.w = pk_bf2(acc[r][ 6], acc[r][ 7]);
      q1.x = pk_bf2(acc[r][ 8], acc[r][ 9]);
      q1.y = pk_bf2(acc[r][10], acc[r][11]);
      q1.z = pk_bf2(acc[r][12], acc[r][13]);
      q1.w = pk_bf2(acc[r][14], acc[r][15]);
      *(uint4*)(dst + 0) = q0;
      *(uint4*)(dst + 4) = q1;
      if (HEADS == 4){
        if ((cg & 1) == 0){
          ASRC[(size_t)row * 4 + (cg >> 1)] = ps;
          ADST[(size_t)row * 4 + (cg >> 1)] = pd;
        }
      } else {
        if (cg == 0){
          ASRC[row] = ps;
          ADST[row] = pd;
        }
      }
    }
  }
}

// ---------------- dst-centric aggregation + bias + ELU (FROZEN) ----------------
// bf16 rows, lane covers 8 channels (one uint4 gather). 2 edge-groups/dst,
// zero-padded batches of 8. OUTBF16: layer1 writes h1a as bf16.

template<int CH, int HEADS, bool OUTBF16>
__global__ __launch_bounds__(256) void k_aggregate(
    const unsigned short* __restrict__ Hmsg, const float* __restrict__ ASRC,
    const float* __restrict__ ADST, const int* __restrict__ off,
    const int* __restrict__ csr, const float* __restrict__ bias,
    void* __restrict__ OUT, int n)
{
  constexpr int CL  = CH / 8;        // lanes per group (16 / 8)
  constexpr int LPD = CL * 2;        // lanes per dst (32 / 16)
  constexpr int DPB = 256 / LPD;     // dsts per block (8 / 16)
  constexpr int CPH = CH / HEADS;    // channels per head (32 / 64)
  constexpr int RQ  = CH / 8;        // uint4 per row

  const int tid  = threadIdx.x;
  const int ld   = tid / LPD;
  const int sub  = tid % LPD;
  const int g    = sub / CL;         // edge group 0/1
  const int cl   = sub % CL;
  const int c0   = cl * 8;
  const int h    = c0 / CPH;
  const int d    = blockIdx.x * DPB + ld;
  if (d >= n) return;

  const uint4* Hv = (const uint4*)Hmsg;
  const float adst = ADST[(size_t)d * HEADS + h];

  float wsum = 0.f;
  float acc[8];
  #pragma unroll
  for (int j = 0; j < 8; ++j) acc[j] = 0.f;

  if (g == 0){
    // self loop
    float t = ASRC[(size_t)d * HEADS + h] + adst;
    float w = __expf(fmaxf(t, 0.2f * t));
    float f[8];
    unpack8(Hv[(size_t)d * RQ + cl], f);
    #pragma unroll
    for (int j = 0; j < 8; ++j) acc[j] = w * f[j];
    wsum = w;
  }

  const int s0 = off[d], s1 = off[d + 1];
  const int cnt = s1 - s0;
  const int lo = s0 + ((cnt * g) >> 1);
  const int hi = s0 + ((cnt * (g + 1)) >> 1);

  for (int p = lo; p < hi; p += 8){
    int  idx[8];
    bool ok[8];
    #pragma unroll
    for (int j = 0; j < 8; ++j){
      int pos = p + j;                          // csr has +8 slack
      int q = csr[pos];
      ok[j]  = pos < hi;
      idx[j] = ok[j] ? q : 0;
    }
    float av[8];
    uint4 hq[8];
    #pragma unroll
    for (int j = 0; j < 8; ++j) av[j] = ASRC[(size_t)idx[j] * HEADS + h];
    #pragma unroll
    for (int j = 0; j < 8; ++j) hq[j] = Hv[(size_t)idx[j] * RQ + cl];
    #pragma unroll
    for (int j = 0; j < 8; ++j){
      float t = av[j] + adst;
      float w = __expf(fmaxf(t, 0.2f * t));
      w = ok[j] ? w : 0.f;
      float f[8];
      unpack8(hq[j], f);
      #pragma unroll
      for (int q = 0; q < 8; ++q) acc[q] = fmaf(w, f[q], acc[q]);
      wsum += w;
    }
  }

  // combine the two edge groups
  #pragma unroll
  for (int j = 0; j < 8; ++j) acc[j] += __shfl_xor(acc[j], CL);
  wsum += __shfl_xor(wsum, CL);

  if (g == 0){
    const float inv = 1.f / (wsum + 1e-16f);
    float o[8];
    #pragma unroll
    for (int j = 0; j < 8; ++j){
      float v = acc[j] * inv + bias[c0 + j];
      o[j] = v > 0.f ? v : expm1f(v);
    }
    if (OUTBF16){
      uint4 q;
      q.x = pk_bf2(o[0], o[1]); q.y = pk_bf2(o[2], o[3]);
      q.z = pk_bf2(o[4], o[5]); q.w = pk_bf2(o[6], o[7]);
      *(uint4*)((unsigned short*)OUT + (size_t)d * CH + c0) = q;
    } else {
      float* Of = (float*)OUT;
      *(float4*)&Of[(size_t)d * CH + c0 + 0] = make_float4(o[0], o[1], o[2], o[3]);
      *(float4*)&Of[(size_t)d * CH + c0 + 4] = make_float4(o[4], o[5], o[6], o[7]);
    }
  }
}

// ---------------- pooling: chunk-parallel partial sums ----------------

__global__ __launch_bounds__(256) void k_pool_partial(
    const float* __restrict__ H, const int* __restrict__ batch,
    float* __restrict__ sums, int n)
{
  constexpr int CHUNK = 256;
  const int c    = threadIdx.x & 63;
  const int slot = threadIdx.x >> 6;    // 4 node-slots
  const int start = blockIdx.x * CHUNK;
  const int end   = min(start + CHUNK, n);

  float acc = 0.f;
  int cur = -1;
  for (int nn = start + slot; nn < end; nn += 4){
    int g = batch[nn];                  // wave-uniform broadcast load
    if (g != cur){                      // wave-uniform branch
      if (cur >= 0) atomicAdd(&sums[cur * 64 + c], acc);
      acc = 0.f; cur = g;
    }
    acc += H[(size_t)nn * 64 + c];
  }
  if (cur >= 0) atomicAdd(&sums[cur * 64 + c], acc);
}

// classify: 128 threads = (graph g, class cls); counts via binary search
__global__ __launch_bounds__(128) void k_classify(
    const float* __restrict__ sums, const int* __restrict__ batch,
    const float* __restrict__ Wc, const float* __restrict__ bc,
    float* __restrict__ out, int n)
{
  int t = threadIdx.x;
  if (t >= 128) return;
  int g = t >> 1, cls = t & 1;
  int lo = 0, hi = n;
  while (lo < hi){ int m = (lo + hi) >> 1; if (batch[m] < g) lo = m + 1; else hi = m; }
  int s = lo;
  lo = s; hi = n;
  while (lo < hi){ int m = (lo + hi) >> 1; if (batch[m] < g + 1) lo = m + 1; else hi = m; }
  int cnt = lo - s;
  float inv = 1.f / (float)(cnt > 1 ? cnt : 1);
  float dot = 0.f;
  #pragma unroll
  for (int c = 0; c < 64; ++c) dot = fmaf(sums[g * 64 + c], Wc[c * 2 + cls], dot);
  out[g * 2 + cls] = dot * inv + bc[cls];
}

// ---------------- launch ----------------

extern "C" void kernel_launch(void* const* d_in, const int* in_sizes, int n_in,
                              void* d_out, int out_size, void* d_ws, size_t ws_size,
                              hipStream_t stream)
{
  const float* x    = (const float*)d_in[0];
  const int*   edge = (const int*)  d_in[1];
  const int*   batch= (const int*)  d_in[2];
  const float* W1   = (const float*)d_in[3];
  const float* as1w = (const float*)d_in[4];
  const float* ad1w = (const float*)d_in[5];
  const float* b1   = (const float*)d_in[6];
  const float* W2   = (const float*)d_in[7];
  const float* as2w = (const float*)d_in[8];
  const float* ad2w = (const float*)d_in[9];
  const float* b2   = (const float*)d_in[10];
  const float* Wc   = (const float*)d_in[11];
  const float* bc   = (const float*)d_in[12];

  const int n = in_sizes[2];          // 100000
  const int e = in_sizes[1] / 2;      // 1600000
  const int* esrc = edge;
  const int* edst = edge + e;

  // workspace layout
  // region A: h1 (n*128 bf16); later h2 (n*64 bf16) aliases it
  // region B: h1a (n*128 bf16); later h2a (n*64 f32) aliases it (same bytes)
  unsigned short* h1  = (unsigned short*)d_ws;              // n*128 bf16
  unsigned short* h1a = h1 + (size_t)n * 128;               // n*128 bf16
  float* as1 = (float*)(h1a + (size_t)n * 128);             // n*4
  float* ad1 = as1 + (size_t)n * 4;                         // n*4
  float* as2 = ad1 + (size_t)n * 4;                         // n
  float* ad2 = as2 + (size_t)n;                             // n
  float* sums = ad2 + (size_t)n;                            // 64*64
  int*  counts = (int*)(sums + 64 * 64);                    // n
  int*  offs   = counts + n;                                // n+1
  int*  tmp    = offs + n + 1;                              // n
  int*  bsum   = tmp + n;                                   // 128
  int*  rank   = bsum + 128;                                // e
  int*  csr    = rank + e;                                  // e + 8 slack

  const int nb = (n + 1023) / 1024;
  const int eb = (e + 255) / 256;

  // CSR build
  hipMemsetAsync(counts, 0, (size_t)n * 4, stream);
  hipMemsetAsync(sums, 0, 64 * 64 * 4, stream);
  k_hist   <<<eb, 256, 0, stream>>>(edst, counts, rank, e);
  k_scan1  <<<nb, 1024, 0, stream>>>(counts, tmp, bsum, n);
  k_scan23 <<<(n + 255) / 256, 256, 0, stream>>>(tmp, bsum, offs, n);
  k_scatter<<<eb, 256, 0, stream>>>(esrc, edst, rank, offs, csr, e);

  // conv1
  k_gemm_att<128, 4, 8, 4, false><<<(n + 127) / 128, 256, 0, stream>>>(
      x, W1, as1w, ad1w, h1, as1, ad1, n);
  k_aggregate<128, 4, true><<<(n + 7) / 8, 256, 0, stream>>>(
      h1, as1, ad1, offs, csr, b1, (void*)h1a, n);

  // conv2 (region reuse)
  unsigned short* h2 = h1;
  float* h2a = (float*)h1a;
  k_gemm_att<64, 1, 4, 2, true><<<(n + 127) / 128, 256, 0, stream>>>(
      h1a, W2, as2w, ad2w, h2, as2, ad2, n);
  k_aggregate<64, 1, false><<<(n + 15) / 16, 256, 0, stream>>>(
      h2, as2, ad2, offs, csr, b2, (void*)h2a, n);

  // pool + classify
  k_pool_partial<<<(n + 255) / 256, 256, 0, stream>>>(h2a, batch, sums, n);
  k_classify<<<1, 128, 0, stream>>>(sums, batch, Wc, bc, (float*)d_out, n);
}

// Round 11
// 445.103 us; speedup vs baseline: 1.4623x; 1.0876x over previous
//
#include <hip/hip_runtime.h>
#include <math.h>

// ---------------------------------------------------------------------------
// GAT 2-layer + mean-pool + classifier.
//  - CSR(dst) built on-device (atomic-free scatter via rank array)
//  - softmax denominators factor out; no segment-max (logits O(1), fp32 safe)
//  - message tables bf16; h1a (layer-2 input) also bf16
//  - aggregation FROZEN at the measured replicated-gather floor (~99 us L1)
//  - GEMMs: MFMA 16x16x32 bf16 (x/W rounded to bf16 in staging; error budget
//    ~6e-3 on h vs threshold-safe 1.16e-4 end-to-end). W staged whole-K in
//    LDS [col][K+8] (272B stride = 2-way/free banks); x per-chunk [row][40].
//    Attention dots shfl-reduced in-wave (wave owns complete rows).
// ---------------------------------------------------------------------------

typedef __attribute__((ext_vector_type(8))) short bf16x8;
typedef __attribute__((ext_vector_type(4))) float f32x4;

__device__ __forceinline__ unsigned f2bf_rne(float x){
  unsigned u = __float_as_uint(x);
  return (u + 0x7fffu + ((u >> 16) & 1u)) >> 16;
}
__device__ __forceinline__ unsigned pk_bf2(float a, float b){
  return f2bf_rne(a) | (f2bf_rne(b) << 16);
}
__device__ __forceinline__ void unpack8(uint4 q, float* f){
  f[0] = __uint_as_float(q.x << 16);
  f[1] = __uint_as_float(q.x & 0xffff0000u);
  f[2] = __uint_as_float(q.y << 16);
  f[3] = __uint_as_float(q.y & 0xffff0000u);
  f[4] = __uint_as_float(q.z << 16);
  f[5] = __uint_as_float(q.z & 0xffff0000u);
  f[6] = __uint_as_float(q.w << 16);
  f[7] = __uint_as_float(q.w & 0xffff0000u);
}

// ---------------- CSR build ----------------

__global__ void k_hist(const int* __restrict__ dst, int* __restrict__ counts,
                       int* __restrict__ rank, int e){
  int i = blockIdx.x * 256 + threadIdx.x;
  if (i < e) rank[i] = atomicAdd(&counts[dst[i]], 1);
}

__global__ __launch_bounds__(1024) void k_scan1(const int* __restrict__ counts,
                                                int* __restrict__ tmp,
                                                int* __restrict__ bsum, int n){
  __shared__ int sh[1024];
  int t = threadIdx.x;
  int i = blockIdx.x * 1024 + t;
  sh[t] = (i < n) ? counts[i] : 0;
  __syncthreads();
  for (int o = 1; o < 1024; o <<= 1){
    int x = (t >= o) ? sh[t - o] : 0;
    __syncthreads();
    sh[t] += x;
    __syncthreads();
  }
  if (i < n) tmp[i] = sh[t];
  if (t == 1023) bsum[blockIdx.x] = sh[t];
}

__global__ void k_scan23(const int* __restrict__ tmp, const int* __restrict__ bsum,
                         int* __restrict__ off, int n){
  int q = blockIdx.x >> 2;
  int bb = 0;
  for (int b = 0; b < q; ++b) bb += bsum[b];
  int i = blockIdx.x * 256 + threadIdx.x;
  if (i < n){
    off[i + 1] = tmp[i] + bb;
    if (i == 0) off[0] = 0;
  }
}

__global__ void k_scatter(const int* __restrict__ src, const int* __restrict__ dst,
                          const int* __restrict__ rank, const int* __restrict__ off,
                          int* __restrict__ csr, int e){
  int i = blockIdx.x * 256 + threadIdx.x;
  if (i < e) csr[off[dst[i]] + rank[i]] = src[i];
}

// ---------------- MFMA GEMM (X @ W) + attention dot epilogue ----------------
// OUTC=128: CT=8 col-tiles, RT=2 row-tiles/wave, 128 rows/block.
// OUTC=64 : CT=4,          RT=4,               256 rows/block.
// Each wave owns WROWS complete rows (all cols) -> attention dots reduce
// in-wave via shfl_xor over the 16 col-lanes.

template<int OUTC, int HEADS, bool XBF16, typename XT>
__global__ __launch_bounds__(256) void k_gemm_mfma(
    const XT* __restrict__ X, const float* __restrict__ W,
    const float* __restrict__ att_s, const float* __restrict__ att_d,
    unsigned short* __restrict__ H, float* __restrict__ ASRC,
    float* __restrict__ ADST, int n)
{
  constexpr int K  = 128;
  constexpr int KC = 32;
  constexpr int CT = OUTC / 16;          // col tiles per wave
  constexpr int RT = 16 / CT;            // row tiles per wave
  constexpr int WROWS = RT * 16;
  constexpr int BROWS = WROWS * 4;

  __shared__ unsigned short Bs[OUTC][K + 8];    // [col][k], 272B stride
  __shared__ unsigned short As[BROWS][KC + 8];  // [row][k], 80B stride

  const int tid   = threadIdx.x;
  const int lane  = tid & 63;
  const int c15   = lane & 15;
  const int quad  = lane >> 4;
  const int warow = (tid >> 6) * WROWS;
  const int row0  = blockIdx.x * BROWS;

  f32x4 acc[CT][RT];
  #pragma unroll
  for (int ct = 0; ct < CT; ++ct)
    #pragma unroll
    for (int t = 0; t < RT; ++t)
      #pragma unroll
      for (int r = 0; r < 4; ++r) acc[ct][t][r] = 0.f;

  // stage ALL of W (bf16, transposed [col][k]) once per block
  for (int idx = tid; idx < K * OUTC / 4; idx += 256){
    int k  = idx / (OUTC / 4);
    int c4 = (idx % (OUTC / 4)) * 4;
    float4 v = *(const float4*)&W[(size_t)k * OUTC + c4];
    Bs[c4 + 0][k] = (unsigned short)f2bf_rne(v.x);
    Bs[c4 + 1][k] = (unsigned short)f2bf_rne(v.y);
    Bs[c4 + 2][k] = (unsigned short)f2bf_rne(v.z);
    Bs[c4 + 3][k] = (unsigned short)f2bf_rne(v.w);
  }

  for (int kc = 0; kc < K; kc += KC){
    // stage X chunk (convert fp32->bf16, or straight bf16 copy)
    if (XBF16){
      for (int idx = tid; idx < BROWS * (KC / 8); idx += 256){
        int rr = idx / (KC / 8);
        int q  = idx % (KC / 8);
        int row = row0 + rr;
        uint4 v = make_uint4(0, 0, 0, 0);
        if (row < n) v = *(const uint4*)((const unsigned short*)X + (size_t)row * K + kc + q * 8);
        *(uint4*)&As[rr][q * 8] = v;
      }
    } else {
      for (int idx = tid; idx < BROWS * (KC / 4); idx += 256){
        int rr = idx / (KC / 4);
        int q  = idx % (KC / 4);
        int row = row0 + rr;
        float4 v = make_float4(0.f, 0.f, 0.f, 0.f);
        if (row < n) v = *(const float4*)((const float*)X + (size_t)row * K + kc + q * 4);
        *(uint2*)&As[rr][q * 4] = make_uint2(pk_bf2(v.x, v.y), pk_bf2(v.z, v.w));
      }
    }
    __syncthreads();

    bf16x8 af[RT];
    #pragma unroll
    for (int t = 0; t < RT; ++t)
      af[t] = *(const bf16x8*)&As[warow + t * 16 + c15][8 * quad];
    #pragma unroll
    for (int ct = 0; ct < CT; ++ct){
      bf16x8 bfr = *(const bf16x8*)&Bs[ct * 16 + c15][kc + 8 * quad];
      #pragma unroll
      for (int t = 0; t < RT; ++t)
        acc[ct][t] = __builtin_amdgcn_mfma_f32_16x16x32_bf16(af[t], bfr, acc[ct][t], 0, 0, 0);
    }
    __syncthreads();
  }

  // epilogue: bf16 H write + in-wave shfl-reduced attention dots
  float ats[CT], atd[CT];
  #pragma unroll
  for (int ct = 0; ct < CT; ++ct){
    ats[ct] = att_s[ct * 16 + c15];
    atd[ct] = att_d[ct * 16 + c15];
  }
  #pragma unroll
  for (int t = 0; t < RT; ++t){
    #pragma unroll
    for (int r = 0; r < 4; ++r){
      int row = row0 + warow + t * 16 + quad * 4 + r;
      float hs[HEADS], hd[HEADS];
      #pragma unroll
      for (int h = 0; h < HEADS; ++h){ hs[h] = 0.f; hd[h] = 0.f; }
      #pragma unroll
      for (int ct = 0; ct < CT; ++ct){
        float v = acc[ct][t][r];
        constexpr int CPH = OUTC / HEADS;
        int h = (ct * 16) / CPH;          // c15 < 16 <= CPH -> head uniform per ct
        hs[h] = fmaf(v, ats[ct], hs[h]);
        hd[h] = fmaf(v, atd[ct], hd[h]);
      }
      #pragma unroll
      for (int h = 0; h < HEADS; ++h){
        #pragma unroll
        for (int s = 1; s < 16; s <<= 1){
          hs[h] += __shfl_xor(hs[h], s);
          hd[h] += __shfl_xor(hd[h], s);
        }
      }
      if (row < n){
        #pragma unroll
        for (int ct = 0; ct < CT; ++ct)
          H[(size_t)row * OUTC + ct * 16 + c15] = (unsigned short)f2bf_rne(acc[ct][t][r]);
        if (c15 == 0){
          #pragma unroll
          for (int h = 0; h < HEADS; ++h){
            ASRC[(size_t)row * HEADS + h] = hs[h];
            ADST[(size_t)row * HEADS + h] = hd[h];
          }
        }
      }
    }
  }
}

// ---------------- dst-centric aggregation + bias + ELU (FROZEN) ----------------

template<int CH, int HEADS, bool OUTBF16>
__global__ __launch_bounds__(256) void k_aggregate(
    const unsigned short* __restrict__ Hmsg, const float* __restrict__ ASRC,
    const float* __restrict__ ADST, const int* __restrict__ off,
    const int* __restrict__ csr, const float* __restrict__ bias,
    void* __restrict__ OUT, int n)
{
  constexpr int CL  = CH / 8;        // lanes per group (16 / 8)
  constexpr int LPD = CL * 2;        // lanes per dst (32 / 16)
  constexpr int DPB = 256 / LPD;     // dsts per block (8 / 16)
  constexpr int CPH = CH / HEADS;    // channels per head
  constexpr int RQ  = CH / 8;        // uint4 per row

  const int tid  = threadIdx.x;
  const int ld   = tid / LPD;
  const int sub  = tid % LPD;
  const int g    = sub / CL;         // edge group 0/1
  const int cl   = sub % CL;
  const int c0   = cl * 8;
  const int h    = c0 / CPH;
  const int d    = blockIdx.x * DPB + ld;
  if (d >= n) return;

  const uint4* Hv = (const uint4*)Hmsg;
  const float adst = ADST[(size_t)d * HEADS + h];

  float wsum = 0.f;
  float acc[8];
  #pragma unroll
  for (int j = 0; j < 8; ++j) acc[j] = 0.f;

  if (g == 0){
    // self loop
    float t = ASRC[(size_t)d * HEADS + h] + adst;
    float w = __expf(fmaxf(t, 0.2f * t));
    float f[8];
    unpack8(Hv[(size_t)d * RQ + cl], f);
    #pragma unroll
    for (int j = 0; j < 8; ++j) acc[j] = w * f[j];
    wsum = w;
  }

  const int s0 = off[d], s1 = off[d + 1];
  const int cnt = s1 - s0;
  const int lo = s0 + ((cnt * g) >> 1);
  const int hi = s0 + ((cnt * (g + 1)) >> 1);

  for (int p = lo; p < hi; p += 8){
    int  idx[8];
    bool ok[8];
    #pragma unroll
    for (int j = 0; j < 8; ++j){
      int pos = p + j;                          // csr has +8 slack
      int q = csr[pos];
      ok[j]  = pos < hi;
      idx[j] = ok[j] ? q : 0;
    }
    float av[8];
    uint4 hq[8];
    #pragma unroll
    for (int j = 0; j < 8; ++j) av[j] = ASRC[(size_t)idx[j] * HEADS + h];
    #pragma unroll
    for (int j = 0; j < 8; ++j) hq[j] = Hv[(size_t)idx[j] * RQ + cl];
    #pragma unroll
    for (int j = 0; j < 8; ++j){
      float t = av[j] + adst;
      float w = __expf(fmaxf(t, 0.2f * t));
      w = ok[j] ? w : 0.f;
      float f[8];
      unpack8(hq[j], f);
      #pragma unroll
      for (int q = 0; q < 8; ++q) acc[q] = fmaf(w, f[q], acc[q]);
      wsum += w;
    }
  }

  // combine the two edge groups
  #pragma unroll
  for (int j = 0; j < 8; ++j) acc[j] += __shfl_xor(acc[j], CL);
  wsum += __shfl_xor(wsum, CL);

  if (g == 0){
    const float inv = 1.f / (wsum + 1e-16f);
    float o[8];
    #pragma unroll
    for (int j = 0; j < 8; ++j){
      float v = acc[j] * inv + bias[c0 + j];
      o[j] = v > 0.f ? v : expm1f(v);
    }
    if (OUTBF16){
      uint4 q;
      q.x = pk_bf2(o[0], o[1]); q.y = pk_bf2(o[2], o[3]);
      q.z = pk_bf2(o[4], o[5]); q.w = pk_bf2(o[6], o[7]);
      *(uint4*)((unsigned short*)OUT + (size_t)d * CH + c0) = q;
    } else {
      float* Of = (float*)OUT;
      *(float4*)&Of[(size_t)d * CH + c0 + 0] = make_float4(o[0], o[1], o[2], o[3]);
      *(float4*)&Of[(size_t)d * CH + c0 + 4] = make_float4(o[4], o[5], o[6], o[7]);
    }
  }
}

// ---------------- pooling: chunk-parallel partial sums ----------------

__global__ __launch_bounds__(256) void k_pool_partial(
    const float* __restrict__ H, const int* __restrict__ batch,
    float* __restrict__ sums, int n)
{
  constexpr int CHUNK = 256;
  const int c    = threadIdx.x & 63;
  const int slot = threadIdx.x >> 6;    // 4 node-slots
  const int start = blockIdx.x * CHUNK;
  const int end   = min(start + CHUNK, n);

  float acc = 0.f;
  int cur = -1;
  for (int nn = start + slot; nn < end; nn += 4){
    int g = batch[nn];                  // wave-uniform broadcast load
    if (g != cur){                      // wave-uniform branch
      if (cur >= 0) atomicAdd(&sums[cur * 64 + c], acc);
      acc = 0.f; cur = g;
    }
    acc += H[(size_t)nn * 64 + c];
  }
  if (cur >= 0) atomicAdd(&sums[cur * 64 + c], acc);
}

// classify: 128 threads = (graph g, class cls); counts via binary search
__global__ __launch_bounds__(128) void k_classify(
    const float* __restrict__ sums, const int* __restrict__ batch,
    const float* __restrict__ Wc, const float* __restrict__ bc,
    float* __restrict__ out, int n)
{
  int t = threadIdx.x;
  if (t >= 128) return;
  int g = t >> 1, cls = t & 1;
  int lo = 0, hi = n;
  while (lo < hi){ int m = (lo + hi) >> 1; if (batch[m] < g) lo = m + 1; else hi = m; }
  int s = lo;
  lo = s; hi = n;
  while (lo < hi){ int m = (lo + hi) >> 1; if (batch[m] < g + 1) lo = m + 1; else hi = m; }
  int cnt = lo - s;
  float inv = 1.f / (float)(cnt > 1 ? cnt : 1);
  float dot = 0.f;
  #pragma unroll
  for (int c = 0; c < 64; ++c) dot = fmaf(sums[g * 64 + c], Wc[c * 2 + cls], dot);
  out[g * 2 + cls] = dot * inv + bc[cls];
}

// ---------------- launch ----------------

extern "C" void kernel_launch(void* const* d_in, const int* in_sizes, int n_in,
                              void* d_out, int out_size, void* d_ws, size_t ws_size,
                              hipStream_t stream)
{
  const float* x    = (const float*)d_in[0];
  const int*   edge = (const int*)  d_in[1];
  const int*   batch= (const int*)  d_in[2];
  const float* W1   = (const float*)d_in[3];
  const float* as1w = (const float*)d_in[4];
  const float* ad1w = (const float*)d_in[5];
  const float* b1   = (const float*)d_in[6];
  const float* W2   = (const float*)d_in[7];
  const float* as2w = (const float*)d_in[8];
  const float* ad2w = (const float*)d_in[9];
  const float* b2   = (const float*)d_in[10];
  const float* Wc   = (const float*)d_in[11];
  const float* bc   = (const float*)d_in[12];

  const int n = in_sizes[2];          // 100000
  const int e = in_sizes[1] / 2;      // 1600000
  const int* esrc = edge;
  const int* edst = edge + e;

  // workspace layout
  unsigned short* h1  = (unsigned short*)d_ws;              // n*128 bf16 (later h2 n*64)
  unsigned short* h1a = h1 + (size_t)n * 128;               // n*128 bf16 (later h2a n*64 f32)
  float* as1 = (float*)(h1a + (size_t)n * 128);             // n*4
  float* ad1 = as1 + (size_t)n * 4;                         // n*4
  float* as2 = ad1 + (size_t)n * 4;                         // n
  float* ad2 = as2 + (size_t)n;                             // n
  float* sums = ad2 + (size_t)n;                            // 64*64
  int*  counts = (int*)(sums + 64 * 64);                    // n
  int*  offs   = counts + n;                                // n+1
  int*  tmp    = offs + n + 1;                              // n
  int*  bsum   = tmp + n;                                   // 128
  int*  rank   = bsum + 128;                                // e
  int*  csr    = rank + e;                                  // e + 8 slack

  const int nb = (n + 1023) / 1024;
  const int eb = (e + 255) / 256;

  // CSR build
  hipMemsetAsync(counts, 0, (size_t)n * 4, stream);
  hipMemsetAsync(sums, 0, 64 * 64 * 4, stream);
  k_hist   <<<eb, 256, 0, stream>>>(edst, counts, rank, e);
  k_scan1  <<<nb, 1024, 0, stream>>>(counts, tmp, bsum, n);
  k_scan23 <<<(n + 255) / 256, 256, 0, stream>>>(tmp, bsum, offs, n);
  k_scatter<<<eb, 256, 0, stream>>>(esrc, edst, rank, offs, csr, e);

  // conv1 (MFMA gemm: 128 rows/block)
  k_gemm_mfma<128, 4, false><<<(n + 127) / 128, 256, 0, stream>>>(
      x, W1, as1w, ad1w, h1, as1, ad1, n);
  k_aggregate<128, 4, true><<<(n + 7) / 8, 256, 0, stream>>>(
      h1, as1, ad1, offs, csr, b1, (void*)h1a, n);

  // conv2 (MFMA gemm: 256 rows/block; region reuse)
  unsigned short* h2 = h1;
  float* h2a = (float*)h1a;
  k_gemm_mfma<64, 1, true><<<(n + 255) / 256, 256, 0, stream>>>(
      h1a, W2, as2w, ad2w, h2, as2, ad2, n);
  k_aggregate<64, 1, false><<<(n + 15) / 16, 256, 0, stream>>>(
      h2, as2, ad2, offs, csr, b2, (void*)h2a, n);

  // pool + classify
  k_pool_partial<<<(n + 255) / 256, 256, 0, stream>>>(h2a, batch, sums, n);
  k_classify<<<1, 128, 0, stream>>>(sums, batch, Wc, bc, (float*)d_out, n);
}

// Round 12
// 401.864 us; speedup vs baseline: 1.6196x; 1.1076x over previous
//
#include <hip/hip_runtime.h>
#include <math.h>

// ---------------------------------------------------------------------------
// GAT 2-layer + mean-pool + classifier.
//  - CSR(dst): bucketed two-pass build (multisplit) — avoids the ~16x line
//    amplification of a flat random scatter (R11 diagnosis: ~150us hidden)
//  - softmax denominators factor out; no segment-max (logits O(1), fp32 safe)
//  - message tables bf16; aggregation FROZEN at the replicated-gather floor
//  - GEMMs: MFMA 16x16x32 bf16
// ---------------------------------------------------------------------------

typedef __attribute__((ext_vector_type(8))) short bf16x8;
typedef __attribute__((ext_vector_type(4))) float f32x4;

__device__ __forceinline__ unsigned f2bf_rne(float x){
  unsigned u = __float_as_uint(x);
  return (u + 0x7fffu + ((u >> 16) & 1u)) >> 16;
}
__device__ __forceinline__ unsigned pk_bf2(float a, float b){
  return f2bf_rne(a) | (f2bf_rne(b) << 16);
}
__device__ __forceinline__ void unpack8(uint4 q, float* f){
  f[0] = __uint_as_float(q.x << 16);
  f[1] = __uint_as_float(q.x & 0xffff0000u);
  f[2] = __uint_as_float(q.y << 16);
  f[3] = __uint_as_float(q.y & 0xffff0000u);
  f[4] = __uint_as_float(q.z << 16);
  f[5] = __uint_as_float(q.z & 0xffff0000u);
  f[6] = __uint_as_float(q.w << 16);
  f[7] = __uint_as_float(q.w & 0xffff0000u);
}

// ---------------- bucketed CSR build ----------------
// bucket b = dst >> 8 (256 dsts/bucket). NB <= 512.
// packed record: src | (dstoff << 17)  (src < 2^17, dstoff < 256)

#define CHUNKE 8192

__global__ __launch_bounds__(256) void k_bucketcount(
    const int* __restrict__ dst, int* __restrict__ bcnt, int e, int NB)
{
  __shared__ int hcnt[512];
  const int tid = threadIdx.x;
  for (int b = tid; b < 512; b += 256) hcnt[b] = 0;
  __syncthreads();
  const int lo = blockIdx.x * CHUNKE;
  const int hi = min(lo + CHUNKE, e);
  for (int i = lo + tid; i < hi; i += 256)
    atomicAdd(&hcnt[dst[i] >> 8], 1);
  __syncthreads();
  for (int b = tid; b < NB; b += 256)
    if (hcnt[b]) atomicAdd(&bcnt[b], hcnt[b]);
}

__global__ __launch_bounds__(512) void k_bucketscan(
    const int* __restrict__ bcnt, int* __restrict__ bbase,
    int* __restrict__ cur, int* __restrict__ off, int e, int n, int NB)
{
  __shared__ int sh[512];
  const int t = threadIdx.x;
  int v = (t < NB) ? bcnt[t] : 0;
  sh[t] = v;
  __syncthreads();
  for (int o = 1; o < 512; o <<= 1){
    int x = (t >= o) ? sh[t - o] : 0;
    __syncthreads();
    sh[t] += x;
    __syncthreads();
  }
  if (t < NB){
    int excl = sh[t] - v;
    bbase[t] = excl;
    cur[t]   = excl;
  }
  if (t == 0) off[n] = e;
}

__global__ __launch_bounds__(256) void k_partition(
    const int* __restrict__ src, const int* __restrict__ dst,
    int* __restrict__ cur, unsigned* __restrict__ packed, int e, int NB)
{
  __shared__ int hcnt[512];
  __shared__ int hbase[512];
  const int tid = threadIdx.x;
  for (int b = tid; b < 512; b += 256) hcnt[b] = 0;
  __syncthreads();
  const int lo = blockIdx.x * CHUNKE;
  const int hi = min(lo + CHUNKE, e);
  for (int i = lo + tid; i < hi; i += 256)
    atomicAdd(&hcnt[dst[i] >> 8], 1);
  __syncthreads();
  for (int b = tid; b < NB; b += 256){
    int c = hcnt[b];
    hbase[b] = c ? atomicAdd(&cur[b], c) : 0;
    hcnt[b] = 0;
  }
  __syncthreads();
  for (int i = lo + tid; i < hi; i += 256){
    int d = dst[i];
    int b = d >> 8;
    int p = hbase[b] + atomicAdd(&hcnt[b], 1);
    packed[p] = (unsigned)src[i] | ((unsigned)(d & 255) << 17);
  }
}

__global__ __launch_bounds__(256) void k_bucketbuild(
    const unsigned* __restrict__ packed, const int* __restrict__ bbase,
    const int* __restrict__ bcnt, int* __restrict__ off,
    int* __restrict__ csr, int n)
{
  __shared__ int lcnt[256];
  __shared__ int loff[256];
  const int b    = blockIdx.x;
  const int tid  = threadIdx.x;
  const int seg0 = bbase[b];
  const int scnt = bcnt[b];

  lcnt[tid] = 0;
  __syncthreads();
  for (int i = tid; i < scnt; i += 256)
    atomicAdd(&lcnt[packed[seg0 + i] >> 17], 1);
  __syncthreads();
  int v = lcnt[tid];
  loff[tid] = v;
  __syncthreads();
  for (int o = 1; o < 256; o <<= 1){
    int x = (tid >= o) ? loff[tid - o] : 0;
    __syncthreads();
    loff[tid] += x;
    __syncthreads();
  }
  int excl = loff[tid] - v;
  __syncthreads();
  loff[tid] = excl;              // exclusive local offsets
  lcnt[tid] = 0;                 // reuse as cursor
  int d = (b << 8) + tid;
  if (d < n) off[d] = seg0 + excl;
  __syncthreads();
  for (int i = tid; i < scnt; i += 256){
    unsigned rec = packed[seg0 + i];
    int doff = rec >> 17;
    int s    = rec & 0x1FFFF;
    int p    = atomicAdd(&lcnt[doff], 1);
    csr[seg0 + loff[doff] + p] = s;
  }
}

// ---------------- MFMA GEMM (X @ W) + attention dot epilogue ----------------

template<int OUTC, int HEADS, bool XBF16, typename XT>
__global__ __launch_bounds__(256) void k_gemm_mfma(
    const XT* __restrict__ X, const float* __restrict__ W,
    const float* __restrict__ att_s, const float* __restrict__ att_d,
    unsigned short* __restrict__ H, float* __restrict__ ASRC,
    float* __restrict__ ADST, int n)
{
  constexpr int K  = 128;
  constexpr int KC = 32;
  constexpr int CT = OUTC / 16;
  constexpr int RT = 16 / CT;
  constexpr int WROWS = RT * 16;
  constexpr int BROWS = WROWS * 4;

  __shared__ unsigned short Bs[OUTC][K + 8];
  __shared__ unsigned short As[BROWS][KC + 8];

  const int tid   = threadIdx.x;
  const int lane  = tid & 63;
  const int c15   = lane & 15;
  const int quad  = lane >> 4;
  const int warow = (tid >> 6) * WROWS;
  const int row0  = blockIdx.x * BROWS;

  f32x4 acc[CT][RT];
  #pragma unroll
  for (int ct = 0; ct < CT; ++ct)
    #pragma unroll
    for (int t = 0; t < RT; ++t)
      #pragma unroll
      for (int r = 0; r < 4; ++r) acc[ct][t][r] = 0.f;

  for (int idx = tid; idx < K * OUTC / 4; idx += 256){
    int k  = idx / (OUTC / 4);
    int c4 = (idx % (OUTC / 4)) * 4;
    float4 v = *(const float4*)&W[(size_t)k * OUTC + c4];
    Bs[c4 + 0][k] = (unsigned short)f2bf_rne(v.x);
    Bs[c4 + 1][k] = (unsigned short)f2bf_rne(v.y);
    Bs[c4 + 2][k] = (unsigned short)f2bf_rne(v.z);
    Bs[c4 + 3][k] = (unsigned short)f2bf_rne(v.w);
  }

  for (int kc = 0; kc < K; kc += KC){
    if (XBF16){
      for (int idx = tid; idx < BROWS * (KC / 8); idx += 256){
        int rr = idx / (KC / 8);
        int q  = idx % (KC / 8);
        int row = row0 + rr;
        uint4 v = make_uint4(0, 0, 0, 0);
        if (row < n) v = *(const uint4*)((const unsigned short*)X + (size_t)row * K + kc + q * 8);
        *(uint4*)&As[rr][q * 8] = v;
      }
    } else {
      for (int idx = tid; idx < BROWS * (KC / 4); idx += 256){
        int rr = idx / (KC / 4);
        int q  = idx % (KC / 4);
        int row = row0 + rr;
        float4 v = make_float4(0.f, 0.f, 0.f, 0.f);
        if (row < n) v = *(const float4*)((const float*)X + (size_t)row * K + kc + q * 4);
        *(uint2*)&As[rr][q * 4] = make_uint2(pk_bf2(v.x, v.y), pk_bf2(v.z, v.w));
      }
    }
    __syncthreads();

    bf16x8 af[RT];
    #pragma unroll
    for (int t = 0; t < RT; ++t)
      af[t] = *(const bf16x8*)&As[warow + t * 16 + c15][8 * quad];
    #pragma unroll
    for (int ct = 0; ct < CT; ++ct){
      bf16x8 bfr = *(const bf16x8*)&Bs[ct * 16 + c15][kc + 8 * quad];
      #pragma unroll
      for (int t = 0; t < RT; ++t)
        acc[ct][t] = __builtin_amdgcn_mfma_f32_16x16x32_bf16(af[t], bfr, acc[ct][t], 0, 0, 0);
    }
    __syncthreads();
  }

  float ats[CT], atd[CT];
  #pragma unroll
  for (int ct = 0; ct < CT; ++ct){
    ats[ct] = att_s[ct * 16 + c15];
    atd[ct] = att_d[ct * 16 + c15];
  }
  #pragma unroll
  for (int t = 0; t < RT; ++t){
    #pragma unroll
    for (int r = 0; r < 4; ++r){
      int row = row0 + warow + t * 16 + quad * 4 + r;
      float hs[HEADS], hd[HEADS];
      #pragma unroll
      for (int h = 0; h < HEADS; ++h){ hs[h] = 0.f; hd[h] = 0.f; }
      #pragma unroll
      for (int ct = 0; ct < CT; ++ct){
        float v = acc[ct][t][r];
        constexpr int CPH = OUTC / HEADS;
        int h = (ct * 16) / CPH;
        hs[h] = fmaf(v, ats[ct], hs[h]);
        hd[h] = fmaf(v, atd[ct], hd[h]);
      }
      #pragma unroll
      for (int h = 0; h < HEADS; ++h){
        #pragma unroll
        for (int s = 1; s < 16; s <<= 1){
          hs[h] += __shfl_xor(hs[h], s);
          hd[h] += __shfl_xor(hd[h], s);
        }
      }
      if (row < n){
        #pragma unroll
        for (int ct = 0; ct < CT; ++ct)
          H[(size_t)row * OUTC + ct * 16 + c15] = (unsigned short)f2bf_rne(acc[ct][t][r]);
        if (c15 == 0){
          #pragma unroll
          for (int h = 0; h < HEADS; ++h){
            ASRC[(size_t)row * HEADS + h] = hs[h];
            ADST[(size_t)row * HEADS + h] = hd[h];
          }
        }
      }
    }
  }
}

// ---------------- dst-centric aggregation + bias + ELU (FROZEN) ----------------

template<int CH, int HEADS, bool OUTBF16>
__global__ __launch_bounds__(256) void k_aggregate(
    const unsigned short* __restrict__ Hmsg, const float* __restrict__ ASRC,
    const float* __restrict__ ADST, const int* __restrict__ off,
    const int* __restrict__ csr, const float* __restrict__ bias,
    void* __restrict__ OUT, int n)
{
  constexpr int CL  = CH / 8;
  constexpr int LPD = CL * 2;
  constexpr int DPB = 256 / LPD;
  constexpr int CPH = CH / HEADS;
  constexpr int RQ  = CH / 8;

  const int tid  = threadIdx.x;
  const int ld   = tid / LPD;
  const int sub  = tid % LPD;
  const int g    = sub / CL;
  const int cl   = sub % CL;
  const int c0   = cl * 8;
  const int h    = c0 / CPH;
  const int d    = blockIdx.x * DPB + ld;
  if (d >= n) return;

  const uint4* Hv = (const uint4*)Hmsg;
  const float adst = ADST[(size_t)d * HEADS + h];

  float wsum = 0.f;
  float acc[8];
  #pragma unroll
  for (int j = 0; j < 8; ++j) acc[j] = 0.f;

  if (g == 0){
    float t = ASRC[(size_t)d * HEADS + h] + adst;
    float w = __expf(fmaxf(t, 0.2f * t));
    float f[8];
    unpack8(Hv[(size_t)d * RQ + cl], f);
    #pragma unroll
    for (int j = 0; j < 8; ++j) acc[j] = w * f[j];
    wsum = w;
  }

  const int s0 = off[d], s1 = off[d + 1];
  const int cnt = s1 - s0;
  const int lo = s0 + ((cnt * g) >> 1);
  const int hi = s0 + ((cnt * (g + 1)) >> 1);

  for (int p = lo; p < hi; p += 8){
    int  idx[8];
    bool ok[8];
    #pragma unroll
    for (int j = 0; j < 8; ++j){
      int pos = p + j;
      int q = csr[pos];
      ok[j]  = pos < hi;
      idx[j] = ok[j] ? q : 0;
    }
    float av[8];
    uint4 hq[8];
    #pragma unroll
    for (int j = 0; j < 8; ++j) av[j] = ASRC[(size_t)idx[j] * HEADS + h];
    #pragma unroll
    for (int j = 0; j < 8; ++j) hq[j] = Hv[(size_t)idx[j] * RQ + cl];
    #pragma unroll
    for (int j = 0; j < 8; ++j){
      float t = av[j] + adst;
      float w = __expf(fmaxf(t, 0.2f * t));
      w = ok[j] ? w : 0.f;
      float f[8];
      unpack8(hq[j], f);
      #pragma unroll
      for (int q = 0; q < 8; ++q) acc[q] = fmaf(w, f[q], acc[q]);
      wsum += w;
    }
  }

  #pragma unroll
  for (int j = 0; j < 8; ++j) acc[j] += __shfl_xor(acc[j], CL);
  wsum += __shfl_xor(wsum, CL);

  if (g == 0){
    const float inv = 1.f / (wsum + 1e-16f);
    float o[8];
    #pragma unroll
    for (int j = 0; j < 8; ++j){
      float v = acc[j] * inv + bias[c0 + j];
      o[j] = v > 0.f ? v : expm1f(v);
    }
    if (OUTBF16){
      uint4 q;
      q.x = pk_bf2(o[0], o[1]); q.y = pk_bf2(o[2], o[3]);
      q.z = pk_bf2(o[4], o[5]); q.w = pk_bf2(o[6], o[7]);
      *(uint4*)((unsigned short*)OUT + (size_t)d * CH + c0) = q;
    } else {
      float* Of = (float*)OUT;
      *(float4*)&Of[(size_t)d * CH + c0 + 0] = make_float4(o[0], o[1], o[2], o[3]);
      *(float4*)&Of[(size_t)d * CH + c0 + 4] = make_float4(o[4], o[5], o[6], o[7]);
    }
  }
}

// ---------------- pooling: chunk-parallel partial sums ----------------

__global__ __launch_bounds__(256) void k_pool_partial(
    const float* __restrict__ H, const int* __restrict__ batch,
    float* __restrict__ sums, int n)
{
  constexpr int CHUNK = 256;
  const int c    = threadIdx.x & 63;
  const int slot = threadIdx.x >> 6;
  const int start = blockIdx.x * CHUNK;
  const int end   = min(start + CHUNK, n);

  float acc = 0.f;
  int cur = -1;
  for (int nn = start + slot; nn < end; nn += 4){
    int g = batch[nn];
    if (g != cur){
      if (cur >= 0) atomicAdd(&sums[cur * 64 + c], acc);
      acc = 0.f; cur = g;
    }
    acc += H[(size_t)nn * 64 + c];
  }
  if (cur >= 0) atomicAdd(&sums[cur * 64 + c], acc);
}

__global__ __launch_bounds__(128) void k_classify(
    const float* __restrict__ sums, const int* __restrict__ batch,
    const float* __restrict__ Wc, const float* __restrict__ bc,
    float* __restrict__ out, int n)
{
  int t = threadIdx.x;
  if (t >= 128) return;
  int g = t >> 1, cls = t & 1;
  int lo = 0, hi = n;
  while (lo < hi){ int m = (lo + hi) >> 1; if (batch[m] < g) lo = m + 1; else hi = m; }
  int s = lo;
  lo = s; hi = n;
  while (lo < hi){ int m = (lo + hi) >> 1; if (batch[m] < g + 1) lo = m + 1; else hi = m; }
  int cnt = lo - s;
  float inv = 1.f / (float)(cnt > 1 ? cnt : 1);
  float dot = 0.f;
  #pragma unroll
  for (int c = 0; c < 64; ++c) dot = fmaf(sums[g * 64 + c], Wc[c * 2 + cls], dot);
  out[g * 2 + cls] = dot * inv + bc[cls];
}

// ---------------- launch ----------------

extern "C" void kernel_launch(void* const* d_in, const int* in_sizes, int n_in,
                              void* d_out, int out_size, void* d_ws, size_t ws_size,
                              hipStream_t stream)
{
  const float* x    = (const float*)d_in[0];
  const int*   edge = (const int*)  d_in[1];
  const int*   batch= (const int*)  d_in[2];
  const float* W1   = (const float*)d_in[3];
  const float* as1w = (const float*)d_in[4];
  const float* ad1w = (const float*)d_in[5];
  const float* b1   = (const float*)d_in[6];
  const float* W2   = (const float*)d_in[7];
  const float* as2w = (const float*)d_in[8];
  const float* ad2w = (const float*)d_in[9];
  const float* b2   = (const float*)d_in[10];
  const float* Wc   = (const float*)d_in[11];
  const float* bc   = (const float*)d_in[12];

  const int n = in_sizes[2];          // 100000
  const int e = in_sizes[1] / 2;      // 1600000
  const int* esrc = edge;
  const int* edst = edge + e;
  const int NB = (n + 255) >> 8;      // 391 buckets

  // workspace layout
  unsigned short* h1  = (unsigned short*)d_ws;              // n*128 bf16 (later h2 n*64)
  unsigned short* h1a = h1 + (size_t)n * 128;               // n*128 bf16 (later h2a n*64 f32)
  float* as1 = (float*)(h1a + (size_t)n * 128);             // n*4
  float* ad1 = as1 + (size_t)n * 4;                         // n*4
  float* as2 = ad1 + (size_t)n * 4;                         // n
  float* ad2 = as2 + (size_t)n;                             // n
  float* sums = ad2 + (size_t)n;                            // 64*64
  int*  bcnt  = (int*)(sums + 64 * 64);                     // 512 (zeroed w/ sums)
  int*  cur   = bcnt + 512;                                 // 512
  int*  bbase = cur + 512;                                  // 512
  int*  off   = bbase + 512;                                // n+1
  unsigned* packed = (unsigned*)(off + n + 1);              // e
  int*  csr   = (int*)(packed + e);                         // e + 8 slack

  const int eb = (e + CHUNKE - 1) / CHUNKE;                 // 196 blocks

  // CSR build (bucketed two-pass)
  hipMemsetAsync(sums, 0, (64 * 64 + 512) * 4, stream);     // sums + bcnt
  k_bucketcount<<<eb, 256, 0, stream>>>(edst, bcnt, e, NB);
  k_bucketscan <<<1, 512, 0, stream>>>(bcnt, bbase, cur, off, e, n, NB);
  k_partition  <<<eb, 256, 0, stream>>>(esrc, edst, cur, packed, e, NB);
  k_bucketbuild<<<NB, 256, 0, stream>>>(packed, bbase, bcnt, off, csr, n);

  // conv1 (MFMA gemm: 128 rows/block)
  k_gemm_mfma<128, 4, false><<<(n + 127) / 128, 256, 0, stream>>>(
      x, W1, as1w, ad1w, h1, as1, ad1, n);
  k_aggregate<128, 4, true><<<(n + 7) / 8, 256, 0, stream>>>(
      h1, as1, ad1, off, csr, b1, (void*)h1a, n);

  // conv2 (MFMA gemm: 256 rows/block; region reuse)
  unsigned short* h2 = h1;
  float* h2a = (float*)h1a;
  k_gemm_mfma<64, 1, true><<<(n + 255) / 256, 256, 0, stream>>>(
      h1a, W2, as2w, ad2w, h2, as2, ad2, n);
  k_aggregate<64, 1, false><<<(n + 15) / 16, 256, 0, stream>>>(
      h2, as2, ad2, off, csr, b2, (void*)h2a, n);

  // pool + classify
  k_pool_partial<<<(n + 255) / 256, 256, 0, stream>>>(h2a, batch, sums, n);
  k_classify<<<1, 128, 0, stream>>>(sums, batch, Wc, bc, (float*)d_out, n);
}